// Round 10
// baseline (484.140 us; speedup 1.0000x reference)
//
#include <hip/hip_runtime.h>

// LayerGIN MoE — round 19: instrumentation split of aggregate (2 halves).
//  * Round-18: CPAD revert confirmed via counters (FETCH 343->335.6 MB,
//    agg 104.5->99.8 us). But total flat at ~480: the OTHER ~381 us across
//    6 dispatches has NEVER been directly profiled — top-5 saturates with
//    5 instances of the single slowest kernel (always aggregate).
//  * This round: aggregate split into two ~50 us half-dispatches (disjoint
//    node ranges; shared read-only v_bf; stream-serial, ~2-4 us overhead).
//    Pigeonhole: at least one non-agg kernel is >= 63 us, so next round's
//    top-5 MUST surface it with full counters. Pure measurement buy.
//  * Everything else byte-identical to round 18 (481.6 us measured).

#define NNODES 51200
#define CDIM   200
#define CPAD   208   // 416 B rows = exactly 7 cache lines at either 0/32 phase
#define HDIM   128
#define NEXP   8
#define BNEPS  1e-5f
#define KC1    26    // K=416 chunks of 16 for A'=[agg;v]
#define KS2    8     // 128/16
#define NB     400   // scatter buckets (128 rows each)
#define CAP    6144  // fixed bucket capacity (mean 4096, sigma 64)
#define EPB    8192  // edges per block, pass A

typedef __attribute__((ext_vector_type(8)))  short short8;
typedef __attribute__((ext_vector_type(16))) float floatx16;
typedef unsigned short ushort_t;

__device__ __forceinline__ ushort_t f2bf(float x) {
  unsigned int u = __float_as_uint(x);
  u += 0x7fffu + ((u >> 16) & 1u);
  return (ushort_t)(u >> 16);
}
__device__ __forceinline__ float bf2f(ushort_t h) {
  return __uint_as_float(((unsigned int)h) << 16);
}

// ------------------------------------------------- gating + v->bf16 convert
__device__ void gating_body(
    int bid, const float* __restrict__ v, const float* __restrict__ gW,
    const float* __restrict__ gb, int* __restrict__ top_idx,
    float* __restrict__ top_val, ushort_t* __restrict__ v_bf,
    float* __restrict__ imp_acc, float* __restrict__ cnt_acc,
    float* __restrict__ tv_acc)
{
  __shared__ float s_imp[NEXP], s_cnt[NEXP], s_tv;
  const int tid = threadIdx.x, lane = tid & 63, wave = tid >> 6;
  if (tid < NEXP) { s_imp[tid] = 0.f; s_cnt[tid] = 0.f; }
  if (tid == 0) s_tv = 0.f;
  __syncthreads();
  const int c0 = lane * 4;
  const bool act = lane < 50;
  float gwr[4][NEXP];
#pragma unroll
  for (int r = 0; r < 4; ++r)
#pragma unroll
    for (int e = 0; e < NEXP; ++e)
      gwr[r][e] = act ? gW[(c0 + r) * NEXP + e] : 0.f;
  for (int i = 0; i < 16; ++i) {
    const int node = bid * 64 + wave * 16 + i;
    float4 x = make_float4(0.f, 0.f, 0.f, 0.f);
    if (act) x = *(const float4*)(v + (size_t)node * CDIM + c0);
    float p[NEXP];
#pragma unroll
    for (int e = 0; e < NEXP; ++e)
      p[e] = fmaf(x.x, gwr[0][e],
             fmaf(x.y, gwr[1][e],
             fmaf(x.z, gwr[2][e], x.w * gwr[3][e])));
#pragma unroll
    for (int off = 32; off > 0; off >>= 1)
#pragma unroll
      for (int e = 0; e < NEXP; ++e) p[e] += __shfl_xor(p[e], off, 64);
#pragma unroll
    for (int e = 0; e < NEXP; ++e) p[e] += gb[e];
    if (lane < 52) {
      ushort4 o = {0, 0, 0, 0};
      if (act) { o.x = f2bf(x.x); o.y = f2bf(x.y); o.z = f2bf(x.z); o.w = f2bf(x.w); }
      *(ushort4*)(v_bf + (size_t)node * CPAD + c0) = o;
    }
    float mx = p[0]; int ai = 0;
#pragma unroll
    for (int e = 1; e < NEXP; ++e) if (p[e] > mx) { mx = p[e]; ai = e; }
    float se = 0.f, pe[NEXP];
#pragma unroll
    for (int e = 0; e < NEXP; ++e) { pe[e] = __expf(p[e] - mx); se += pe[e]; }
    const float inv = 1.f / se;
    if (lane == 0) {
      top_idx[node] = ai;
      top_val[node] = inv;
#pragma unroll
      for (int e = 0; e < NEXP; ++e) atomicAdd(&s_imp[e], pe[e] * inv);
      atomicAdd(&s_cnt[ai], 1.f);
      atomicAdd(&s_tv, inv);
    }
  }
  __syncthreads();
  if (tid < NEXP) { atomicAdd(&imp_acc[tid], s_imp[tid]); atomicAdd(&cnt_acc[tid], s_cnt[tid]); }
  if (tid == 0) atomicAdd(tv_acc, s_tv);
}

// -------------------- weight prep body: W1 stacked [W1;se*W1] + W2 plain
__device__ void btconv_body(
    int j, int e, const float* __restrict__ W1, const float* __restrict__ W2,
    const float* __restrict__ eps, ushort_t* __restrict__ Bt1,
    ushort_t* __restrict__ Bt2)
{
  __shared__ float tile[16][128];
  const int tid = threadIdx.x;
  const int kr = tid >> 5, n4 = (tid & 31) * 4;
  const float* W; int K, jj; float sc; ushort_t* dst;
  if (j < KC1) {
    sc = (j >= 13) ? (1.f + eps[e]) : 1.f;
    jj = (j >= 13) ? (j - 13) : j;
    W = W1; K = CDIM;
    dst = Bt1 + (((size_t)e * KC1 + j) * 256) * 8;
  } else {
    sc = 1.f; jj = j - KC1; W = W2; K = HDIM;
    dst = Bt2 + (((size_t)e * KS2 + jj) * 256) * 8;
  }
#pragma unroll
  for (int h = 0; h < 2; ++h) {
    const int k = jj * 16 + kr + h * 8;
    float4 val = make_float4(0.f, 0.f, 0.f, 0.f);
    if (k < K) val = *(const float4*)(W + ((size_t)e * K + k) * HDIM + n4);
    *(float4*)&tile[kr + h * 8][n4] = val;
  }
  __syncthreads();
  const int kh = tid >> 7, n = tid & 127;
  short8 pk;
#pragma unroll
  for (int q = 0; q < 8; ++q) pk[q] = (short)f2bf(sc * tile[kh * 8 + q][n]);
  *(short8*)(dst + (size_t)tid * 8) = pk;
}

// ---- pass A body: coarse bucket scatter into fixed-capacity bucket slots ----
__device__ void bucketA_body(
    int bid, const int* __restrict__ rows, const int* __restrict__ cols,
    const float* __restrict__ vals, int* __restrict__ bcnt,
    int2* __restrict__ tmp, int ne)
{
  __shared__ int cnt[NB];
  __shared__ int gbase[NB];
  const int tid = threadIdx.x;
  const int base = bid * EPB;
  for (int b = tid; b < NB; b += 256) cnt[b] = 0;
  __syncthreads();
#pragma unroll 4
  for (int j = 0; j < EPB / 256; ++j) {
    const int i = base + j * 256 + tid;
    if (i < ne) atomicAdd(&cnt[rows[i] >> 7], 1);
  }
  __syncthreads();
  for (int b = tid; b < NB; b += 256) {
    const int c = cnt[b];
    gbase[b] = c ? (b * CAP + atomicAdd(&bcnt[b], c)) : 0;
    cnt[b] = 0;
  }
  __syncthreads();
#pragma unroll 4
  for (int j = 0; j < EPB / 256; ++j) {
    const int i = base + j * 256 + tid;
    if (i < ne) {
      const int r = rows[i];
      const int b = r >> 7;
      const int pos = gbase[b] + atomicAdd(&cnt[b], 1);
      tmp[pos] = make_int2((r << 16) | cols[i], __float_as_int(vals[i]));
    }
  }
}

// ---- merged front-end: [gating nGat | btconv 272 | bucketA nA] ----
__global__ __launch_bounds__(256) void prep_kernel(
    const float* __restrict__ v, const float* __restrict__ gW,
    const float* __restrict__ gb, int* __restrict__ top_idx,
    float* __restrict__ top_val, ushort_t* __restrict__ v_bf,
    float* __restrict__ imp_acc, float* __restrict__ cnt_acc,
    float* __restrict__ tv_acc,
    const float* __restrict__ W1, const float* __restrict__ W2,
    const float* __restrict__ eps, ushort_t* __restrict__ Bt1,
    ushort_t* __restrict__ Bt2,
    const int* __restrict__ rows, const int* __restrict__ cols,
    const float* __restrict__ vals, int* __restrict__ bcnt,
    int2* __restrict__ tmp, int ne, int nGat)
{
  const int bid = blockIdx.x;
  if (bid < nGat) {
    gating_body(bid, v, gW, gb, top_idx, top_val, v_bf, imp_acc, cnt_acc, tv_acc);
  } else if (bid < nGat + (KC1 + KS2) * NEXP) {
    const int b2 = bid - nGat;
    btconv_body(b2 % (KC1 + KS2), b2 / (KC1 + KS2), W1, W2, eps, Bt1, Bt2);
  } else {
    bucketA_body(bid - nGat - (KC1 + KS2) * NEXP, rows, cols, vals, bcnt, tmp, ne);
  }
}

// ---- pass B: register-resident bucket; local hist+scan -> row_start/counts,
//      then LDS-cursor scatter into cv
__global__ __launch_bounds__(256) void bucketB_kernel(
    const int2* __restrict__ tmp, const int* __restrict__ bcnt,
    int2* __restrict__ cv, int* __restrict__ row_start, int* __restrict__ counts)
{
  __shared__ int lhist[128];
  __shared__ int lcur[128];
  const int tid = threadIdx.x;
  const int b = blockIdx.x;
  const int n = bcnt[b];
  const int base = b * CAP;
  int2 ed[CAP / 256];
#pragma unroll
  for (int j = 0; j < CAP / 256; ++j) {
    const int i = j * 256 + tid;
    if (i < n) ed[j] = tmp[base + i];
  }
  if (tid < 128) lhist[tid] = 0;
  __syncthreads();
#pragma unroll
  for (int j = 0; j < CAP / 256; ++j)
    if (j * 256 + tid < n)
      atomicAdd(&lhist[(((unsigned)ed[j].x) >> 16) & 127], 1);
  __syncthreads();
  if (tid == 0) {
    int acc = base;
    for (int r = 0; r < 128; ++r) { lcur[r] = acc; acc += lhist[r]; }
  }
  __syncthreads();
  if (tid < 128) {
    row_start[(b << 7) + tid] = lcur[tid];
    counts[(b << 7) + tid] = lhist[tid];
  }
  __syncthreads();
#pragma unroll
  for (int j = 0; j < CAP / 256; ++j)
    if (j * 256 + tid < n) {
      const int r = (((unsigned)ed[j].x) >> 16) & 127;
      const int pos = atomicAdd(&lcur[r], 1);
      cv[pos] = make_int2(ed[j].x & 0xffff, ed[j].y);
    }
}

// aggregate v4: one wave per destination node, 2 edges per gather instruction,
// lane-distributed edge prefetch. node0 = node-range offset (split dispatch).
__global__ __launch_bounds__(256) void aggregate_kernel(
    const ushort_t* __restrict__ v_bf, const int2* __restrict__ cv,
    const int* __restrict__ row_start, const int* __restrict__ counts,
    ushort_t* __restrict__ agg_bf, int node0)
{
  const int node = node0 + ((blockIdx.x * 256 + threadIdx.x) >> 6);
  const int lane = threadIdx.x & 63;
  const int half = lane >> 5;
  const int l32  = lane & 31;
  const bool act = l32 < 26;                // 26 lanes x 8 elems = 208
  const int start = row_start[node];
  const int cnt   = counts[node];

  float acc[8];
#pragma unroll
  for (int j = 0; j < 8; ++j) acc[j] = 0.f;

  int ecol = 0, eval = 0;
  if (lane < cnt) {
    const int2 e = cv[start + lane];
    ecol = e.x; eval = e.y;
  }
  const int n64 = cnt < 64 ? cnt : 64;
  int k = 0;

  for (; k + 16 <= n64; k += 16) {
    short8 xx[8];
#pragma unroll
    for (int u = 0; u < 8; ++u) {
      const int cc = __shfl(ecol, k + 2 * u + half, 64);
      short8 t = {0, 0, 0, 0, 0, 0, 0, 0};
      if (act) t = *(const short8*)(v_bf + (size_t)cc * CPAD + l32 * 8);
      xx[u] = t;
    }
#pragma unroll
    for (int u = 0; u < 8; ++u) {
      const float vv = __int_as_float(__shfl(eval, k + 2 * u + half, 64));
#pragma unroll
      for (int j = 0; j < 8; ++j)
        acc[j] = fmaf(vv, bf2f((ushort_t)xx[u][j]), acc[j]);
    }
  }
  for (; k + 4 <= n64; k += 4) {
    short8 xx[2];
#pragma unroll
    for (int u = 0; u < 2; ++u) {
      const int cc = __shfl(ecol, k + 2 * u + half, 64);
      short8 t = {0, 0, 0, 0, 0, 0, 0, 0};
      if (act) t = *(const short8*)(v_bf + (size_t)cc * CPAD + l32 * 8);
      xx[u] = t;
    }
#pragma unroll
    for (int u = 0; u < 2; ++u) {
      const float vv = __int_as_float(__shfl(eval, k + 2 * u + half, 64));
#pragma unroll
      for (int j = 0; j < 8; ++j)
        acc[j] = fmaf(vv, bf2f((ushort_t)xx[u][j]), acc[j]);
    }
  }
  for (; k < n64; k += 2) {
    const int idx = k + half;
    const int cc = __shfl(ecol, idx, 64);
    short8 t = {0, 0, 0, 0, 0, 0, 0, 0};
    if (act) t = *(const short8*)(v_bf + (size_t)cc * CPAD + l32 * 8);
    const float vv = __int_as_float(__shfl(eval, idx, 64));
#pragma unroll
    for (int j = 0; j < 8; ++j)
      acc[j] = fmaf(vv, bf2f((ushort_t)t[j]), acc[j]);
  }
  for (; k < cnt; ++k) {
    const int2 e0 = cv[start + k];
    short8 x0 = {0, 0, 0, 0, 0, 0, 0, 0};
    if (act && half == 0)
      x0 = *(const short8*)(v_bf + (size_t)e0.x * CPAD + l32 * 8);
    const float v0 = half ? 0.f : __int_as_float(e0.y);
#pragma unroll
    for (int j = 0; j < 8; ++j)
      acc[j] = fmaf(v0, bf2f((ushort_t)x0[j]), acc[j]);
  }

#pragma unroll
  for (int j = 0; j < 8; ++j) acc[j] += __shfl_xor(acc[j], 32, 64);

  if (act && half == 0) {
    short8 o;
#pragma unroll
    for (int j = 0; j < 8; ++j) o[j] = (short)f2bf(acc[j]);
    *(short8*)(agg_bf + (size_t)node * CPAD + l32 * 8) = o;
  }
}

// ---------------------------------------------- GEMM 1: occupancy-split
// acc[2][2] (64 AGPR) + ~70 VGPR => 3 blocks/CU at __launch_bounds__(256,3)
// (LDS caps at 3x53 KB = 159/160 KB). Each wave: 4 serial (e, N-half) tasks.
__global__ __launch_bounds__(256, 3) void gemm1_mfma(
    const ushort_t* __restrict__ agg_bf, const ushort_t* __restrict__ v_bf,
    const ushort_t* __restrict__ Bt1x, ushort_t* __restrict__ h1,
    float* __restrict__ sum1, float* __restrict__ sq1)
{
  const int m0 = blockIdx.x * 64;
  __shared__ ushort_t sA[52 * 64 * 8];       // 53248 B
  const int tid = threadIdx.x;
  const int lane = tid & 63, wid = tid >> 6;
  const int l31 = lane & 31, half = lane >> 5;

#pragma unroll
  for (int it = 0; it < 13; ++it) {
    const int l = it * 256 + tid;
    const int g = l >> 6, m = l & 63;
    const ushort_t* src = (g < 26)
        ? agg_bf + (size_t)(m0 + m) * CPAD + g * 8
        : v_bf  + (size_t)(m0 + m) * CPAD + (g - 26) * 8;
    *(short8*)(sA + (size_t)l * 8) = *(const short8*)src;
  }
  __syncthreads();

#pragma unroll 1
  for (int t = 0; t < 4; ++t) {
    const int e  = wid + (t >> 1) * 4;     // t=0,1 -> e=wid; t=2,3 -> e=wid+4
    const int nh = t & 1;
    floatx16 acc[2][2];
#pragma unroll
    for (int ms = 0; ms < 2; ++ms)
#pragma unroll
      for (int ns = 0; ns < 2; ++ns)
#pragma unroll
        for (int r = 0; r < 16; ++r) acc[ms][ns][r] = 0.f;

    const ushort_t* bte =
        Bt1x + ((size_t)e * KC1 * 256 + half * 128 + nh * 64 + l31) * 8;
    short8 nb0 = *(const short8*)(bte);
    short8 nb1 = *(const short8*)(bte + 32 * 8);
#pragma unroll
    for (int j = 0; j < KC1; ++j) {
      const short8 b0 = nb0, b1 = nb1;
      if (j < KC1 - 1) {
        nb0 = *(const short8*)(bte + (size_t)((j + 1) * 256) * 8);
        nb1 = *(const short8*)(bte + (size_t)((j + 1) * 256 + 32) * 8);
      }
      const short8 a0 = *(const short8*)(sA + (size_t)((2 * j + half) * 64 + l31) * 8);
      const short8 a1 = *(const short8*)(sA + (size_t)((2 * j + half) * 64 + 32 + l31) * 8);
      acc[0][0] = __builtin_amdgcn_mfma_f32_32x32x16_bf16(a0, b0, acc[0][0], 0, 0, 0);
      acc[0][1] = __builtin_amdgcn_mfma_f32_32x32x16_bf16(a0, b1, acc[0][1], 0, 0, 0);
      acc[1][0] = __builtin_amdgcn_mfma_f32_32x32x16_bf16(a1, b0, acc[1][0], 0, 0, 0);
      acc[1][1] = __builtin_amdgcn_mfma_f32_32x32x16_bf16(a1, b1, acc[1][1], 0, 0, 0);
    }

    ushort_t* h1e = h1 + ((size_t)e * NNODES + m0) * HDIM;
#pragma unroll
    for (int ns = 0; ns < 2; ++ns) {
      const int col = nh * 64 + ns * 32 + l31;
      float s = 0.f, q = 0.f;
#pragma unroll
      for (int ms = 0; ms < 2; ++ms) {
#pragma unroll
        for (int r = 0; r < 16; ++r) {
          const int row = ms * 32 + (r & 3) + 8 * (r >> 2) + 4 * half;
          const float x = acc[ms][ns][r];
          h1e[(size_t)row * HDIM + col] = f2bf(x);
          s += x; q = fmaf(x, x, q);
        }
      }
      s += __shfl_xor(s, 32, 64);
      q += __shfl_xor(q, 32, 64);
      if (half == 0) {
        atomicAdd(&sum1[e * HDIM + col], s);
        atomicAdd(&sq1[e * HDIM + col], q);
      }
    }
  }
}

// ------------- GEMM 2: BN1 finalize in prologue + single-barrier A staging
__global__ __launch_bounds__(256, 4) void gemm2_mfma(
    const ushort_t* __restrict__ h1, const ushort_t* __restrict__ Bt2,
    const float* __restrict__ sum1, const float* __restrict__ sq1,
    const float* __restrict__ g1, const float* __restrict__ beta1,
    const int* __restrict__ top_idx, float* __restrict__ h2_sel,
    float* __restrict__ sum2, float* __restrict__ sq2)
{
  const int e = blockIdx.y;
  const int m0 = blockIdx.x * 128;
  __shared__ ushort_t sA[16 * 129 * 8];     // 33024 B
  __shared__ float ssum[HDIM], ssq[HDIM];
  __shared__ float sSc[HDIM], sSh[HDIM];
  __shared__ int sTop[128];
  const int tid = threadIdx.x;
  const int lane = tid & 63, wid = tid >> 6;
  const int wm = wid >> 1, wn = wid & 1;
  const int l31 = lane & 31, half = lane >> 5;
  if (tid < HDIM) {
    ssum[tid] = 0.f; ssq[tid] = 0.f;
    sTop[tid] = top_idx[m0 + tid];
    const int i = e * HDIM + tid;
    const float invN = 1.f / (float)NNODES;
    const float mean = sum1[i] * invN;
    const float var  = sq1[i] * invN - mean * mean;
    const float sc = rsqrtf(var + BNEPS) * g1[i];
    sSc[tid] = sc;
    sSh[tid] = fmaf(-mean, sc, beta1[i]);
  }
  __syncthreads();
  {
    const int g = tid & 15, r0 = tid >> 4;
    const float4 sc0 = *(const float4*)&sSc[g * 8];
    const float4 sc1 = *(const float4*)&sSc[g * 8 + 4];
    const float4 sh0 = *(const float4*)&sSh[g * 8];
    const float4 sh1 = *(const float4*)&sSh[g * 8 + 4];
#pragma unroll
    for (int c = 0; c < 8; ++c) {
      const int m = c * 16 + r0;
      const short8 hq = *(const short8*)(
          h1 + ((size_t)e * NNODES + m0 + m) * HDIM + g * 8);
      short8 pk;
      pk[0] = (short)f2bf(fmaxf(0.f, fmaf(bf2f((ushort_t)hq[0]), sc0.x, sh0.x)));
      pk[1] = (short)f2bf(fmaxf(0.f, fmaf(bf2f((ushort_t)hq[1]), sc0.y, sh0.y)));
      pk[2] = (short)f2bf(fmaxf(0.f, fmaf(bf2f((ushort_t)hq[2]), sc0.z, sh0.z)));
      pk[3] = (short)f2bf(fmaxf(0.f, fmaf(bf2f((ushort_t)hq[3]), sc0.w, sh0.w)));
      pk[4] = (short)f2bf(fmaxf(0.f, fmaf(bf2f((ushort_t)hq[4]), sc1.x, sh1.x)));
      pk[5] = (short)f2bf(fmaxf(0.f, fmaf(bf2f((ushort_t)hq[5]), sc1.y, sh1.y)));
      pk[6] = (short)f2bf(fmaxf(0.f, fmaf(bf2f((ushort_t)hq[6]), sc1.z, sh1.z)));
      pk[7] = (short)f2bf(fmaxf(0.f, fmaf(bf2f((ushort_t)hq[7]), sc1.w, sh1.w)));
      *(short8*)(sA + (size_t)(g * 129 + m) * 8) = pk;
    }
  }
  __syncthreads();

  floatx16 acc[2][2];
#pragma unroll
  for (int i = 0; i < 2; ++i)
#pragma unroll
    for (int j = 0; j < 2; ++j)
#pragma unroll
      for (int r = 0; r < 16; ++r) acc[i][j][r] = 0.f;

  const ushort_t* bte = Bt2 + ((size_t)e * KS2 * 256 + half * 128 + wn * 64 + l31) * 8;
  short8 nb0 = *(const short8*)(bte);
  short8 nb1 = *(const short8*)(bte + 32 * 8);
#pragma unroll
  for (int ks = 0; ks < KS2; ++ks) {
    const short8 b0 = nb0, b1 = nb1;
    if (ks < KS2 - 1) {
      nb0 = *(const short8*)(bte + (size_t)((ks + 1) * 256) * 8);
      nb1 = *(const short8*)(bte + (size_t)((ks + 1) * 256 + 32) * 8);
    }
    const short8 a0 = *(const short8*)(sA + (size_t)((2 * ks + half) * 129 + wm * 64 + l31) * 8);
    const short8 a1 = *(const short8*)(sA + (size_t)((2 * ks + half) * 129 + wm * 64 + 32 + l31) * 8);
    acc[0][0] = __builtin_amdgcn_mfma_f32_32x32x16_bf16(a0, b0, acc[0][0], 0, 0, 0);
    acc[0][1] = __builtin_amdgcn_mfma_f32_32x32x16_bf16(a0, b1, acc[0][1], 0, 0, 0);
    acc[1][0] = __builtin_amdgcn_mfma_f32_32x32x16_bf16(a1, b0, acc[1][0], 0, 0, 0);
    acc[1][1] = __builtin_amdgcn_mfma_f32_32x32x16_bf16(a1, b1, acc[1][1], 0, 0, 0);
  }

#pragma unroll
  for (int ms = 0; ms < 2; ++ms)
#pragma unroll
    for (int ns = 0; ns < 2; ++ns) {
      const int col = wn * 64 + ns * 32 + l31;
      float s = 0.f, q = 0.f;
#pragma unroll
      for (int r = 0; r < 16; ++r) {
        const int row = wm * 64 + ms * 32 + (r & 3) + 8 * (r >> 2) + 4 * half;
        const float x = acc[ms][ns][r];
        if (sTop[row] == e) h2_sel[(size_t)(m0 + row) * HDIM + col] = x;
        s += x; q = fmaf(x, x, q);
      }
      atomicAdd(&ssum[col], s);
      atomicAdd(&ssq[col], q);
    }
  __syncthreads();
  if (tid < HDIM) atomicAdd(&sum2[e * HDIM + tid], ssum[tid]);
  else            atomicAdd(&sq2[e * HDIM + tid - HDIM], ssq[tid - HDIM]);
}

// --------------------- combine: BN2 finalize in prologue + gate + aux losses
__global__ __launch_bounds__(256) void combine_kernel(
    const float* __restrict__ h2_sel, const int* __restrict__ top_idx,
    const float* __restrict__ top_val, const float* __restrict__ sum2,
    const float* __restrict__ sq2, const float* __restrict__ g2,
    const float* __restrict__ beta2, const float* __restrict__ imp,
    const float* __restrict__ cntv, const float* __restrict__ tv,
    float* __restrict__ out)
{
  __shared__ float s2[NEXP * HDIM], b2s[NEXP * HDIM];
  const int tid = threadIdx.x;
  const float invN = 1.f / (float)NNODES;
  for (int t = tid; t < NEXP * HDIM; t += 256) {
    const float mean = sum2[t] * invN;
    const float var  = sq2[t] * invN - mean * mean;
    const float sc = rsqrtf(var + BNEPS) * g2[t];
    s2[t] = sc;
    b2s[t] = fmaf(-mean, sc, beta2[t]);
  }
  __syncthreads();
  const int i4 = (blockIdx.x * 256 + tid) * 4;
  const int n = i4 >> 7, h = i4 & 127;
  const int e = top_idx[n];
  const float tvv = top_val[n];
  const float4 x = *(const float4*)(h2_sel + i4);
  const float* sc = s2 + e * HDIM + h;
  const float* sh = b2s + e * HDIM + h;
  float4 o;
  o.x = tvv * fmaxf(0.f, fmaf(x.x, sc[0], sh[0]));
  o.y = tvv * fmaxf(0.f, fmaf(x.y, sc[1], sh[1]));
  o.z = tvv * fmaxf(0.f, fmaf(x.z, sc[2], sh[2]));
  o.w = tvv * fmaxf(0.f, fmaf(x.w, sc[3], sh[3]));
  *(float4*)(out + i4) = o;
  if (blockIdx.x == 0 && tid == 0) {
    float bal = 0.f;
#pragma unroll
    for (int q = 0; q < NEXP; ++q) bal += (imp[q] * invN) * (cntv[q] * invN);
    out[(size_t)NNODES * HDIM]     = 0.01f * (float)NEXP * bal;
    out[(size_t)NNODES * HDIM + 1] = -0.01f * tv[0] * invN;
  }
}

// ----------------------------------------------------------------- launch
struct WS {
  ushort_t *v_bf, *agg_bf, *h1, *Bt1x, *Bt2;
  float *h2_sel;
  int2 *cv, *tmp;
  int *row_start, *counts, *top_idx;
  float *top_val;
  char *zero_base; size_t zero_bytes;
  int *bcnt;
  float *sum1, *sq1, *sum2, *sq2, *imp, *cnt, *tv;
  size_t total;
};

static WS carve_ws(char* base)
{
  WS w; size_t off = 0;
  auto take = [&](size_t b) -> char* {
    char* r = base + off; off += (b + 255) & ~(size_t)255; return r;
  };
  // v_bf (21.3 MB) + agg_bf (21.3 MB) adjacent; h2_sel alias (26.2 MB f32)
  // spills from v_bf into agg_bf, which is dead after gemm1.
  w.v_bf   = (ushort_t*)take((size_t)NNODES * CPAD * 2);
  w.agg_bf = (ushort_t*)take((size_t)NNODES * CPAD * 2);
  w.h2_sel = (float*)w.v_bf;
  w.h1     = (ushort_t*)take((size_t)NEXP * NNODES * HDIM * 2);
  w.cv     = (int2*)take((size_t)NB * CAP * 8);
  w.tmp    = (int2*)take((size_t)NB * CAP * 8);
  w.Bt1x   = (ushort_t*)take((size_t)NEXP * KC1 * 2048 * 2);
  w.Bt2    = (ushort_t*)take((size_t)NEXP * KS2 * 2048 * 2);
  w.row_start = (int*)take(NNODES * 4);
  w.counts    = (int*)take(NNODES * 4);
  w.top_idx   = (int*)take(NNODES * 4);
  w.top_val   = (float*)take(NNODES * 4);
  w.zero_base = base + off;
  w.bcnt = (int*)take(NB * 4);
  w.sum1 = (float*)take(NEXP * HDIM * 4);
  w.sq1  = (float*)take(NEXP * HDIM * 4);
  w.sum2 = (float*)take(NEXP * HDIM * 4);
  w.sq2  = (float*)take(NEXP * HDIM * 4);
  w.imp  = (float*)take(NEXP * 4);
  w.cnt  = (float*)take(NEXP * 4);
  w.tv   = (float*)take(4);
  w.zero_bytes = (size_t)((base + off) - w.zero_base);
  w.total = off;
  return w;
}

extern "C" void kernel_launch(void* const* d_in, const int* in_sizes, int n_in,
                              void* d_out, int out_size, void* d_ws, size_t ws_size,
                              hipStream_t stream)
{
  const float* v      = (const float*)d_in[0];
  const int*   a_rows = (const int*)d_in[1];
  const int*   a_cols = (const int*)d_in[2];
  const float* a_vals = (const float*)d_in[3];
  const float* gate_W = (const float*)d_in[4];
  const float* gate_b = (const float*)d_in[5];
  const float* eps    = (const float*)d_in[6];
  const float* W1     = (const float*)d_in[7];
  const float* g1     = (const float*)d_in[9];
  const float* beta1  = (const float*)d_in[10];
  const float* W2     = (const float*)d_in[11];
  const float* g2     = (const float*)d_in[13];
  const float* beta2  = (const float*)d_in[14];
  const int NE = in_sizes[1];
  float* out = (float*)d_out;
  (void)n_in; (void)out_size; (void)ws_size;

  WS w = carve_ws((char*)d_ws);

  hipMemsetAsync(w.zero_base, 0, w.zero_bytes, stream);

  const int nGat = NNODES / 64;                       // 800
  const int nBtc = (KC1 + KS2) * NEXP;                // 272
  const int nA   = (NE + EPB - 1) / EPB;              // 200
  prep_kernel<<<nGat + nBtc + nA, 256, 0, stream>>>(
      v, gate_W, gate_b, w.top_idx, w.top_val, w.v_bf, w.imp, w.cnt, w.tv,
      W1, W2, eps, w.Bt1x, w.Bt2,
      a_rows, a_cols, a_vals, w.bcnt, w.tmp, NE, nGat);

  bucketB_kernel<<<NB, 256, 0, stream>>>(
      w.tmp, w.bcnt, w.cv, w.row_start, w.counts);

  // aggregate split into two half-dispatches (instrumentation: caps each
  // instance at ~50 us so the true #2 kernel surfaces in top-5 profiling)
  aggregate_kernel<<<NNODES / 8, 256, 0, stream>>>(
      w.v_bf, w.cv, w.row_start, w.counts, w.agg_bf, 0);
  aggregate_kernel<<<NNODES / 8, 256, 0, stream>>>(
      w.v_bf, w.cv, w.row_start, w.counts, w.agg_bf, NNODES / 2);

  gemm1_mfma<<<NNODES / 64, 256, 0, stream>>>(
      w.agg_bf, w.v_bf, w.Bt1x, w.h1, w.sum1, w.sq1);
  gemm2_mfma<<<dim3(NNODES / 128, NEXP), 256, 0, stream>>>(
      w.h1, w.Bt2, w.sum1, w.sq1, g1, beta1, w.top_idx,
      w.h2_sel, w.sum2, w.sq2);
  combine_kernel<<<(NNODES * HDIM) / 1024, 256, 0, stream>>>(
      w.h2_sel, w.top_idx, w.top_val, w.sum2, w.sq2, g2, beta2,
      w.imp, w.cnt, w.tv, out);
}

// Round 11
// 466.637 us; speedup vs baseline: 1.0375x; 1.0375x over previous
//
#include <hip/hip_runtime.h>

// LayerGIN MoE — round 20: kill gemm2's contended global atomics.
//  * Round-19 instrumentation: gemm2 = 89 us with ALL pipes idle (Mfma 5.8%,
//    VALU 18%, HBM 11.6%, Occ 37%) -> ~50K cycles/block latency. Theory:
//    819K device-scope atomicAdds funneled into 16 lines/expert (sum2/sq2),
//    ~400 concurrent same-expert blocks -> line-serialized at the coherence
//    point; waves idle in vmcnt drain (invisible to pipe counters).
//  * Fix: gemm2 stores per-block partials (part2[e][bx][256], coalesced,
//    non-atomic); new reduce2_kernel (8x4 blocks, unrolled 100-row sums,
//    4-way atomics into memset'd sum2/sq2) finalizes. combine unchanged.
//  * aggregate kept split (2 halves) one more round: lets gemm1 surface in
//    top-5 (it has 1.6M atomics to sum1/sq1 — same disease suspected).
//  * everything else byte-identical to round 19 (484.1 us measured).

#define NNODES 51200
#define CDIM   200
#define CPAD   208   // 416 B rows = exactly 7 cache lines at either 0/32 phase
#define HDIM   128
#define NEXP   8
#define BNEPS  1e-5f
#define KC1    26    // K=416 chunks of 16 for A'=[agg;v]
#define KS2    8     // 128/16
#define NB     400   // scatter buckets (128 rows each)
#define CAP    6144  // fixed bucket capacity (mean 4096, sigma 64)
#define EPB    8192  // edges per block, pass A
#define NBX2   400   // gemm2 grid.x = NNODES/128

typedef __attribute__((ext_vector_type(8)))  short short8;
typedef __attribute__((ext_vector_type(16))) float floatx16;
typedef unsigned short ushort_t;

__device__ __forceinline__ ushort_t f2bf(float x) {
  unsigned int u = __float_as_uint(x);
  u += 0x7fffu + ((u >> 16) & 1u);
  return (ushort_t)(u >> 16);
}
__device__ __forceinline__ float bf2f(ushort_t h) {
  return __uint_as_float(((unsigned int)h) << 16);
}

// ------------------------------------------------- gating + v->bf16 convert
__device__ void gating_body(
    int bid, const float* __restrict__ v, const float* __restrict__ gW,
    const float* __restrict__ gb, int* __restrict__ top_idx,
    float* __restrict__ top_val, ushort_t* __restrict__ v_bf,
    float* __restrict__ imp_acc, float* __restrict__ cnt_acc,
    float* __restrict__ tv_acc)
{
  __shared__ float s_imp[NEXP], s_cnt[NEXP], s_tv;
  const int tid = threadIdx.x, lane = tid & 63, wave = tid >> 6;
  if (tid < NEXP) { s_imp[tid] = 0.f; s_cnt[tid] = 0.f; }
  if (tid == 0) s_tv = 0.f;
  __syncthreads();
  const int c0 = lane * 4;
  const bool act = lane < 50;
  float gwr[4][NEXP];
#pragma unroll
  for (int r = 0; r < 4; ++r)
#pragma unroll
    for (int e = 0; e < NEXP; ++e)
      gwr[r][e] = act ? gW[(c0 + r) * NEXP + e] : 0.f;
  for (int i = 0; i < 16; ++i) {
    const int node = bid * 64 + wave * 16 + i;
    float4 x = make_float4(0.f, 0.f, 0.f, 0.f);
    if (act) x = *(const float4*)(v + (size_t)node * CDIM + c0);
    float p[NEXP];
#pragma unroll
    for (int e = 0; e < NEXP; ++e)
      p[e] = fmaf(x.x, gwr[0][e],
             fmaf(x.y, gwr[1][e],
             fmaf(x.z, gwr[2][e], x.w * gwr[3][e])));
#pragma unroll
    for (int off = 32; off > 0; off >>= 1)
#pragma unroll
      for (int e = 0; e < NEXP; ++e) p[e] += __shfl_xor(p[e], off, 64);
#pragma unroll
    for (int e = 0; e < NEXP; ++e) p[e] += gb[e];
    if (lane < 52) {
      ushort4 o = {0, 0, 0, 0};
      if (act) { o.x = f2bf(x.x); o.y = f2bf(x.y); o.z = f2bf(x.z); o.w = f2bf(x.w); }
      *(ushort4*)(v_bf + (size_t)node * CPAD + c0) = o;
    }
    float mx = p[0]; int ai = 0;
#pragma unroll
    for (int e = 1; e < NEXP; ++e) if (p[e] > mx) { mx = p[e]; ai = e; }
    float se = 0.f, pe[NEXP];
#pragma unroll
    for (int e = 0; e < NEXP; ++e) { pe[e] = __expf(p[e] - mx); se += pe[e]; }
    const float inv = 1.f / se;
    if (lane == 0) {
      top_idx[node] = ai;
      top_val[node] = inv;
#pragma unroll
      for (int e = 0; e < NEXP; ++e) atomicAdd(&s_imp[e], pe[e] * inv);
      atomicAdd(&s_cnt[ai], 1.f);
      atomicAdd(&s_tv, inv);
    }
  }
  __syncthreads();
  if (tid < NEXP) { atomicAdd(&imp_acc[tid], s_imp[tid]); atomicAdd(&cnt_acc[tid], s_cnt[tid]); }
  if (tid == 0) atomicAdd(tv_acc, s_tv);
}

// -------------------- weight prep body: W1 stacked [W1;se*W1] + W2 plain
__device__ void btconv_body(
    int j, int e, const float* __restrict__ W1, const float* __restrict__ W2,
    const float* __restrict__ eps, ushort_t* __restrict__ Bt1,
    ushort_t* __restrict__ Bt2)
{
  __shared__ float tile[16][128];
  const int tid = threadIdx.x;
  const int kr = tid >> 5, n4 = (tid & 31) * 4;
  const float* W; int K, jj; float sc; ushort_t* dst;
  if (j < KC1) {
    sc = (j >= 13) ? (1.f + eps[e]) : 1.f;
    jj = (j >= 13) ? (j - 13) : j;
    W = W1; K = CDIM;
    dst = Bt1 + (((size_t)e * KC1 + j) * 256) * 8;
  } else {
    sc = 1.f; jj = j - KC1; W = W2; K = HDIM;
    dst = Bt2 + (((size_t)e * KS2 + jj) * 256) * 8;
  }
#pragma unroll
  for (int h = 0; h < 2; ++h) {
    const int k = jj * 16 + kr + h * 8;
    float4 val = make_float4(0.f, 0.f, 0.f, 0.f);
    if (k < K) val = *(const float4*)(W + ((size_t)e * K + k) * HDIM + n4);
    *(float4*)&tile[kr + h * 8][n4] = val;
  }
  __syncthreads();
  const int kh = tid >> 7, n = tid & 127;
  short8 pk;
#pragma unroll
  for (int q = 0; q < 8; ++q) pk[q] = (short)f2bf(sc * tile[kh * 8 + q][n]);
  *(short8*)(dst + (size_t)tid * 8) = pk;
}

// ---- pass A body: coarse bucket scatter into fixed-capacity bucket slots ----
__device__ void bucketA_body(
    int bid, const int* __restrict__ rows, const int* __restrict__ cols,
    const float* __restrict__ vals, int* __restrict__ bcnt,
    int2* __restrict__ tmp, int ne)
{
  __shared__ int cnt[NB];
  __shared__ int gbase[NB];
  const int tid = threadIdx.x;
  const int base = bid * EPB;
  for (int b = tid; b < NB; b += 256) cnt[b] = 0;
  __syncthreads();
#pragma unroll 4
  for (int j = 0; j < EPB / 256; ++j) {
    const int i = base + j * 256 + tid;
    if (i < ne) atomicAdd(&cnt[rows[i] >> 7], 1);
  }
  __syncthreads();
  for (int b = tid; b < NB; b += 256) {
    const int c = cnt[b];
    gbase[b] = c ? (b * CAP + atomicAdd(&bcnt[b], c)) : 0;
    cnt[b] = 0;
  }
  __syncthreads();
#pragma unroll 4
  for (int j = 0; j < EPB / 256; ++j) {
    const int i = base + j * 256 + tid;
    if (i < ne) {
      const int r = rows[i];
      const int b = r >> 7;
      const int pos = gbase[b] + atomicAdd(&cnt[b], 1);
      tmp[pos] = make_int2((r << 16) | cols[i], __float_as_int(vals[i]));
    }
  }
}

// ---- merged front-end: [gating nGat | btconv 272 | bucketA nA] ----
__global__ __launch_bounds__(256) void prep_kernel(
    const float* __restrict__ v, const float* __restrict__ gW,
    const float* __restrict__ gb, int* __restrict__ top_idx,
    float* __restrict__ top_val, ushort_t* __restrict__ v_bf,
    float* __restrict__ imp_acc, float* __restrict__ cnt_acc,
    float* __restrict__ tv_acc,
    const float* __restrict__ W1, const float* __restrict__ W2,
    const float* __restrict__ eps, ushort_t* __restrict__ Bt1,
    ushort_t* __restrict__ Bt2,
    const int* __restrict__ rows, const int* __restrict__ cols,
    const float* __restrict__ vals, int* __restrict__ bcnt,
    int2* __restrict__ tmp, int ne, int nGat)
{
  const int bid = blockIdx.x;
  if (bid < nGat) {
    gating_body(bid, v, gW, gb, top_idx, top_val, v_bf, imp_acc, cnt_acc, tv_acc);
  } else if (bid < nGat + (KC1 + KS2) * NEXP) {
    const int b2 = bid - nGat;
    btconv_body(b2 % (KC1 + KS2), b2 / (KC1 + KS2), W1, W2, eps, Bt1, Bt2);
  } else {
    bucketA_body(bid - nGat - (KC1 + KS2) * NEXP, rows, cols, vals, bcnt, tmp, ne);
  }
}

// ---- pass B: register-resident bucket; local hist+scan -> row_start/counts,
//      then LDS-cursor scatter into cv
__global__ __launch_bounds__(256) void bucketB_kernel(
    const int2* __restrict__ tmp, const int* __restrict__ bcnt,
    int2* __restrict__ cv, int* __restrict__ row_start, int* __restrict__ counts)
{
  __shared__ int lhist[128];
  __shared__ int lcur[128];
  const int tid = threadIdx.x;
  const int b = blockIdx.x;
  const int n = bcnt[b];
  const int base = b * CAP;
  int2 ed[CAP / 256];
#pragma unroll
  for (int j = 0; j < CAP / 256; ++j) {
    const int i = j * 256 + tid;
    if (i < n) ed[j] = tmp[base + i];
  }
  if (tid < 128) lhist[tid] = 0;
  __syncthreads();
#pragma unroll
  for (int j = 0; j < CAP / 256; ++j)
    if (j * 256 + tid < n)
      atomicAdd(&lhist[(((unsigned)ed[j].x) >> 16) & 127], 1);
  __syncthreads();
  if (tid == 0) {
    int acc = base;
    for (int r = 0; r < 128; ++r) { lcur[r] = acc; acc += lhist[r]; }
  }
  __syncthreads();
  if (tid < 128) {
    row_start[(b << 7) + tid] = lcur[tid];
    counts[(b << 7) + tid] = lhist[tid];
  }
  __syncthreads();
#pragma unroll
  for (int j = 0; j < CAP / 256; ++j)
    if (j * 256 + tid < n) {
      const int r = (((unsigned)ed[j].x) >> 16) & 127;
      const int pos = atomicAdd(&lcur[r], 1);
      cv[pos] = make_int2(ed[j].x & 0xffff, ed[j].y);
    }
}

// aggregate v4: one wave per destination node, 2 edges per gather instruction,
// lane-distributed edge prefetch. node0 = node-range offset (split dispatch).
__global__ __launch_bounds__(256) void aggregate_kernel(
    const ushort_t* __restrict__ v_bf, const int2* __restrict__ cv,
    const int* __restrict__ row_start, const int* __restrict__ counts,
    ushort_t* __restrict__ agg_bf, int node0)
{
  const int node = node0 + ((blockIdx.x * 256 + threadIdx.x) >> 6);
  const int lane = threadIdx.x & 63;
  const int half = lane >> 5;
  const int l32  = lane & 31;
  const bool act = l32 < 26;                // 26 lanes x 8 elems = 208
  const int start = row_start[node];
  const int cnt   = counts[node];

  float acc[8];
#pragma unroll
  for (int j = 0; j < 8; ++j) acc[j] = 0.f;

  int ecol = 0, eval = 0;
  if (lane < cnt) {
    const int2 e = cv[start + lane];
    ecol = e.x; eval = e.y;
  }
  const int n64 = cnt < 64 ? cnt : 64;
  int k = 0;

  for (; k + 16 <= n64; k += 16) {
    short8 xx[8];
#pragma unroll
    for (int u = 0; u < 8; ++u) {
      const int cc = __shfl(ecol, k + 2 * u + half, 64);
      short8 t = {0, 0, 0, 0, 0, 0, 0, 0};
      if (act) t = *(const short8*)(v_bf + (size_t)cc * CPAD + l32 * 8);
      xx[u] = t;
    }
#pragma unroll
    for (int u = 0; u < 8; ++u) {
      const float vv = __int_as_float(__shfl(eval, k + 2 * u + half, 64));
#pragma unroll
      for (int j = 0; j < 8; ++j)
        acc[j] = fmaf(vv, bf2f((ushort_t)xx[u][j]), acc[j]);
    }
  }
  for (; k + 4 <= n64; k += 4) {
    short8 xx[2];
#pragma unroll
    for (int u = 0; u < 2; ++u) {
      const int cc = __shfl(ecol, k + 2 * u + half, 64);
      short8 t = {0, 0, 0, 0, 0, 0, 0, 0};
      if (act) t = *(const short8*)(v_bf + (size_t)cc * CPAD + l32 * 8);
      xx[u] = t;
    }
#pragma unroll
    for (int u = 0; u < 2; ++u) {
      const float vv = __int_as_float(__shfl(eval, k + 2 * u + half, 64));
#pragma unroll
      for (int j = 0; j < 8; ++j)
        acc[j] = fmaf(vv, bf2f((ushort_t)xx[u][j]), acc[j]);
    }
  }
  for (; k < n64; k += 2) {
    const int idx = k + half;
    const int cc = __shfl(ecol, idx, 64);
    short8 t = {0, 0, 0, 0, 0, 0, 0, 0};
    if (act) t = *(const short8*)(v_bf + (size_t)cc * CPAD + l32 * 8);
    const float vv = __int_as_float(__shfl(eval, idx, 64));
#pragma unroll
    for (int j = 0; j < 8; ++j)
      acc[j] = fmaf(vv, bf2f((ushort_t)t[j]), acc[j]);
  }
  for (; k < cnt; ++k) {
    const int2 e0 = cv[start + k];
    short8 x0 = {0, 0, 0, 0, 0, 0, 0, 0};
    if (act && half == 0)
      x0 = *(const short8*)(v_bf + (size_t)e0.x * CPAD + l32 * 8);
    const float v0 = half ? 0.f : __int_as_float(e0.y);
#pragma unroll
    for (int j = 0; j < 8; ++j)
      acc[j] = fmaf(v0, bf2f((ushort_t)x0[j]), acc[j]);
  }

#pragma unroll
  for (int j = 0; j < 8; ++j) acc[j] += __shfl_xor(acc[j], 32, 64);

  if (act && half == 0) {
    short8 o;
#pragma unroll
    for (int j = 0; j < 8; ++j) o[j] = (short)f2bf(acc[j]);
    *(short8*)(agg_bf + (size_t)node * CPAD + l32 * 8) = o;
  }
}

// ---------------------------------------------- GEMM 1: occupancy-split
// acc[2][2] (64 AGPR) + ~70 VGPR => 3 blocks/CU at __launch_bounds__(256,3)
// (LDS caps at 3x53 KB = 159/160 KB). Each wave: 4 serial (e, N-half) tasks.
__global__ __launch_bounds__(256, 3) void gemm1_mfma(
    const ushort_t* __restrict__ agg_bf, const ushort_t* __restrict__ v_bf,
    const ushort_t* __restrict__ Bt1x, ushort_t* __restrict__ h1,
    float* __restrict__ sum1, float* __restrict__ sq1)
{
  const int m0 = blockIdx.x * 64;
  __shared__ ushort_t sA[52 * 64 * 8];       // 53248 B
  const int tid = threadIdx.x;
  const int lane = tid & 63, wid = tid >> 6;
  const int l31 = lane & 31, half = lane >> 5;

#pragma unroll
  for (int it = 0; it < 13; ++it) {
    const int l = it * 256 + tid;
    const int g = l >> 6, m = l & 63;
    const ushort_t* src = (g < 26)
        ? agg_bf + (size_t)(m0 + m) * CPAD + g * 8
        : v_bf  + (size_t)(m0 + m) * CPAD + (g - 26) * 8;
    *(short8*)(sA + (size_t)l * 8) = *(const short8*)src;
  }
  __syncthreads();

#pragma unroll 1
  for (int t = 0; t < 4; ++t) {
    const int e  = wid + (t >> 1) * 4;     // t=0,1 -> e=wid; t=2,3 -> e=wid+4
    const int nh = t & 1;
    floatx16 acc[2][2];
#pragma unroll
    for (int ms = 0; ms < 2; ++ms)
#pragma unroll
      for (int ns = 0; ns < 2; ++ns)
#pragma unroll
        for (int r = 0; r < 16; ++r) acc[ms][ns][r] = 0.f;

    const ushort_t* bte =
        Bt1x + ((size_t)e * KC1 * 256 + half * 128 + nh * 64 + l31) * 8;
    short8 nb0 = *(const short8*)(bte);
    short8 nb1 = *(const short8*)(bte + 32 * 8);
#pragma unroll
    for (int j = 0; j < KC1; ++j) {
      const short8 b0 = nb0, b1 = nb1;
      if (j < KC1 - 1) {
        nb0 = *(const short8*)(bte + (size_t)((j + 1) * 256) * 8);
        nb1 = *(const short8*)(bte + (size_t)((j + 1) * 256 + 32) * 8);
      }
      const short8 a0 = *(const short8*)(sA + (size_t)((2 * j + half) * 64 + l31) * 8);
      const short8 a1 = *(const short8*)(sA + (size_t)((2 * j + half) * 64 + 32 + l31) * 8);
      acc[0][0] = __builtin_amdgcn_mfma_f32_32x32x16_bf16(a0, b0, acc[0][0], 0, 0, 0);
      acc[0][1] = __builtin_amdgcn_mfma_f32_32x32x16_bf16(a0, b1, acc[0][1], 0, 0, 0);
      acc[1][0] = __builtin_amdgcn_mfma_f32_32x32x16_bf16(a1, b0, acc[1][0], 0, 0, 0);
      acc[1][1] = __builtin_amdgcn_mfma_f32_32x32x16_bf16(a1, b1, acc[1][1], 0, 0, 0);
    }

    ushort_t* h1e = h1 + ((size_t)e * NNODES + m0) * HDIM;
#pragma unroll
    for (int ns = 0; ns < 2; ++ns) {
      const int col = nh * 64 + ns * 32 + l31;
      float s = 0.f, q = 0.f;
#pragma unroll
      for (int ms = 0; ms < 2; ++ms) {
#pragma unroll
        for (int r = 0; r < 16; ++r) {
          const int row = ms * 32 + (r & 3) + 8 * (r >> 2) + 4 * half;
          const float x = acc[ms][ns][r];
          h1e[(size_t)row * HDIM + col] = f2bf(x);
          s += x; q = fmaf(x, x, q);
        }
      }
      s += __shfl_xor(s, 32, 64);
      q += __shfl_xor(q, 32, 64);
      if (half == 0) {
        atomicAdd(&sum1[e * HDIM + col], s);
        atomicAdd(&sq1[e * HDIM + col], q);
      }
    }
  }
}

// ------------- GEMM 2: BN1 finalize in prologue + single-barrier A staging.
// Global atomics REPLACED by per-block partial stores (part2) — round-19
// counters showed 89 us with all pipes idle = atomic line contention.
__global__ __launch_bounds__(256, 4) void gemm2_mfma(
    const ushort_t* __restrict__ h1, const ushort_t* __restrict__ Bt2,
    const float* __restrict__ sum1, const float* __restrict__ sq1,
    const float* __restrict__ g1, const float* __restrict__ beta1,
    const int* __restrict__ top_idx, float* __restrict__ h2_sel,
    float* __restrict__ part2)
{
  const int e = blockIdx.y;
  const int m0 = blockIdx.x * 128;
  __shared__ ushort_t sA[16 * 129 * 8];     // 33024 B
  __shared__ float ssum[HDIM], ssq[HDIM];
  __shared__ float sSc[HDIM], sSh[HDIM];
  __shared__ int sTop[128];
  const int tid = threadIdx.x;
  const int lane = tid & 63, wid = tid >> 6;
  const int wm = wid >> 1, wn = wid & 1;
  const int l31 = lane & 31, half = lane >> 5;
  if (tid < HDIM) {
    ssum[tid] = 0.f; ssq[tid] = 0.f;
    sTop[tid] = top_idx[m0 + tid];
    const int i = e * HDIM + tid;
    const float invN = 1.f / (float)NNODES;
    const float mean = sum1[i] * invN;
    const float var  = sq1[i] * invN - mean * mean;
    const float sc = rsqrtf(var + BNEPS) * g1[i];
    sSc[tid] = sc;
    sSh[tid] = fmaf(-mean, sc, beta1[i]);
  }
  __syncthreads();
  {
    const int g = tid & 15, r0 = tid >> 4;
    const float4 sc0 = *(const float4*)&sSc[g * 8];
    const float4 sc1 = *(const float4*)&sSc[g * 8 + 4];
    const float4 sh0 = *(const float4*)&sSh[g * 8];
    const float4 sh1 = *(const float4*)&sSh[g * 8 + 4];
#pragma unroll
    for (int c = 0; c < 8; ++c) {
      const int m = c * 16 + r0;
      const short8 hq = *(const short8*)(
          h1 + ((size_t)e * NNODES + m0 + m) * HDIM + g * 8);
      short8 pk;
      pk[0] = (short)f2bf(fmaxf(0.f, fmaf(bf2f((ushort_t)hq[0]), sc0.x, sh0.x)));
      pk[1] = (short)f2bf(fmaxf(0.f, fmaf(bf2f((ushort_t)hq[1]), sc0.y, sh0.y)));
      pk[2] = (short)f2bf(fmaxf(0.f, fmaf(bf2f((ushort_t)hq[2]), sc0.z, sh0.z)));
      pk[3] = (short)f2bf(fmaxf(0.f, fmaf(bf2f((ushort_t)hq[3]), sc0.w, sh0.w)));
      pk[4] = (short)f2bf(fmaxf(0.f, fmaf(bf2f((ushort_t)hq[4]), sc1.x, sh1.x)));
      pk[5] = (short)f2bf(fmaxf(0.f, fmaf(bf2f((ushort_t)hq[5]), sc1.y, sh1.y)));
      pk[6] = (short)f2bf(fmaxf(0.f, fmaf(bf2f((ushort_t)hq[6]), sc1.z, sh1.z)));
      pk[7] = (short)f2bf(fmaxf(0.f, fmaf(bf2f((ushort_t)hq[7]), sc1.w, sh1.w)));
      *(short8*)(sA + (size_t)(g * 129 + m) * 8) = pk;
    }
  }
  __syncthreads();

  floatx16 acc[2][2];
#pragma unroll
  for (int i = 0; i < 2; ++i)
#pragma unroll
    for (int j = 0; j < 2; ++j)
#pragma unroll
      for (int r = 0; r < 16; ++r) acc[i][j][r] = 0.f;

  const ushort_t* bte = Bt2 + ((size_t)e * KS2 * 256 + half * 128 + wn * 64 + l31) * 8;
  short8 nb0 = *(const short8*)(bte);
  short8 nb1 = *(const short8*)(bte + 32 * 8);
#pragma unroll
  for (int ks = 0; ks < KS2; ++ks) {
    const short8 b0 = nb0, b1 = nb1;
    if (ks < KS2 - 1) {
      nb0 = *(const short8*)(bte + (size_t)((ks + 1) * 256) * 8);
      nb1 = *(const short8*)(bte + (size_t)((ks + 1) * 256 + 32) * 8);
    }
    const short8 a0 = *(const short8*)(sA + (size_t)((2 * ks + half) * 129 + wm * 64 + l31) * 8);
    const short8 a1 = *(const short8*)(sA + (size_t)((2 * ks + half) * 129 + wm * 64 + 32 + l31) * 8);
    acc[0][0] = __builtin_amdgcn_mfma_f32_32x32x16_bf16(a0, b0, acc[0][0], 0, 0, 0);
    acc[0][1] = __builtin_amdgcn_mfma_f32_32x32x16_bf16(a0, b1, acc[0][1], 0, 0, 0);
    acc[1][0] = __builtin_amdgcn_mfma_f32_32x32x16_bf16(a1, b0, acc[1][0], 0, 0, 0);
    acc[1][1] = __builtin_amdgcn_mfma_f32_32x32x16_bf16(a1, b1, acc[1][1], 0, 0, 0);
  }

#pragma unroll
  for (int ms = 0; ms < 2; ++ms)
#pragma unroll
    for (int ns = 0; ns < 2; ++ns) {
      const int col = wn * 64 + ns * 32 + l31;
      float s = 0.f, q = 0.f;
#pragma unroll
      for (int r = 0; r < 16; ++r) {
        const int row = wm * 64 + ms * 32 + (r & 3) + 8 * (r >> 2) + 4 * half;
        const float x = acc[ms][ns][r];
        if (sTop[row] == e) h2_sel[(size_t)(m0 + row) * HDIM + col] = x;
        s += x; q = fmaf(x, x, q);
      }
      atomicAdd(&ssum[col], s);
      atomicAdd(&ssq[col], q);
    }
  __syncthreads();
  // non-atomic coalesced partial store: [e][bx][0:128]=sum, [128:256]=sq
  part2[((size_t)(e * NBX2 + blockIdx.x)) * 256 + tid] =
      (tid < HDIM) ? ssum[tid] : ssq[tid - HDIM];
}

// ---- reduce2: sum part2 over the 400 gemm2 blocks -> sum2/sq2 (memset'd).
// grid (NEXP, 4): each block reduces 100 rows, then 4-way-trivial atomics.
__global__ __launch_bounds__(256) void reduce2_kernel(
    const float* __restrict__ part2, float* __restrict__ sum2,
    float* __restrict__ sq2)
{
  const int e = blockIdx.x, q = blockIdx.y, tid = threadIdx.x;
  const float* base = part2 + ((size_t)(e * NBX2 + q * (NBX2 / 4))) * 256 + tid;
  float a0 = 0.f, a1 = 0.f, a2 = 0.f, a3 = 0.f;
#pragma unroll 1
  for (int b = 0; b < NBX2 / 4; b += 4) {
    a0 += base[(size_t)(b + 0) * 256];
    a1 += base[(size_t)(b + 1) * 256];
    a2 += base[(size_t)(b + 2) * 256];
    a3 += base[(size_t)(b + 3) * 256];
  }
  const float acc = (a0 + a1) + (a2 + a3);
  if (tid < HDIM) atomicAdd(&sum2[e * HDIM + tid], acc);
  else            atomicAdd(&sq2[e * HDIM + tid - HDIM], acc);
}

// --------------------- combine: BN2 finalize in prologue + gate + aux losses
__global__ __launch_bounds__(256) void combine_kernel(
    const float* __restrict__ h2_sel, const int* __restrict__ top_idx,
    const float* __restrict__ top_val, const float* __restrict__ sum2,
    const float* __restrict__ sq2, const float* __restrict__ g2,
    const float* __restrict__ beta2, const float* __restrict__ imp,
    const float* __restrict__ cntv, const float* __restrict__ tv,
    float* __restrict__ out)
{
  __shared__ float s2[NEXP * HDIM], b2s[NEXP * HDIM];
  const int tid = threadIdx.x;
  const float invN = 1.f / (float)NNODES;
  for (int t = tid; t < NEXP * HDIM; t += 256) {
    const float mean = sum2[t] * invN;
    const float var  = sq2[t] * invN - mean * mean;
    const float sc = rsqrtf(var + BNEPS) * g2[t];
    s2[t] = sc;
    b2s[t] = fmaf(-mean, sc, beta2[t]);
  }
  __syncthreads();
  const int i4 = (blockIdx.x * 256 + tid) * 4;
  const int n = i4 >> 7, h = i4 & 127;
  const int e = top_idx[n];
  const float tvv = top_val[n];
  const float4 x = *(const float4*)(h2_sel + i4);
  const float* sc = s2 + e * HDIM + h;
  const float* sh = b2s + e * HDIM + h;
  float4 o;
  o.x = tvv * fmaxf(0.f, fmaf(x.x, sc[0], sh[0]));
  o.y = tvv * fmaxf(0.f, fmaf(x.y, sc[1], sh[1]));
  o.z = tvv * fmaxf(0.f, fmaf(x.z, sc[2], sh[2]));
  o.w = tvv * fmaxf(0.f, fmaf(x.w, sc[3], sh[3]));
  *(float4*)(out + i4) = o;
  if (blockIdx.x == 0 && tid == 0) {
    float bal = 0.f;
#pragma unroll
    for (int q = 0; q < NEXP; ++q) bal += (imp[q] * invN) * (cntv[q] * invN);
    out[(size_t)NNODES * HDIM]     = 0.01f * (float)NEXP * bal;
    out[(size_t)NNODES * HDIM + 1] = -0.01f * tv[0] * invN;
  }
}

// ----------------------------------------------------------------- launch
struct WS {
  ushort_t *v_bf, *agg_bf, *h1, *Bt1x, *Bt2;
  float *h2_sel, *part2;
  int2 *cv, *tmp;
  int *row_start, *counts, *top_idx;
  float *top_val;
  char *zero_base; size_t zero_bytes;
  int *bcnt;
  float *sum1, *sq1, *sum2, *sq2, *imp, *cnt, *tv;
  size_t total;
};

static WS carve_ws(char* base)
{
  WS w; size_t off = 0;
  auto take = [&](size_t b) -> char* {
    char* r = base + off; off += (b + 255) & ~(size_t)255; return r;
  };
  // v_bf (21.3 MB) + agg_bf (21.3 MB) adjacent; h2_sel alias (26.2 MB f32)
  // spills from v_bf into agg_bf, which is dead after gemm1.
  w.v_bf   = (ushort_t*)take((size_t)NNODES * CPAD * 2);
  w.agg_bf = (ushort_t*)take((size_t)NNODES * CPAD * 2);
  w.h2_sel = (float*)w.v_bf;
  w.h1     = (ushort_t*)take((size_t)NEXP * NNODES * HDIM * 2);
  w.cv     = (int2*)take((size_t)NB * CAP * 8);
  w.tmp    = (int2*)take((size_t)NB * CAP * 8);
  w.Bt1x   = (ushort_t*)take((size_t)NEXP * KC1 * 2048 * 2);
  w.Bt2    = (ushort_t*)take((size_t)NEXP * KS2 * 2048 * 2);
  w.part2  = (float*)take((size_t)NEXP * NBX2 * 256 * 4);   // 3.3 MB, fully written
  w.row_start = (int*)take(NNODES * 4);
  w.counts    = (int*)take(NNODES * 4);
  w.top_idx   = (int*)take(NNODES * 4);
  w.top_val   = (float*)take(NNODES * 4);
  w.zero_base = base + off;
  w.bcnt = (int*)take(NB * 4);
  w.sum1 = (float*)take(NEXP * HDIM * 4);
  w.sq1  = (float*)take(NEXP * HDIM * 4);
  w.sum2 = (float*)take(NEXP * HDIM * 4);
  w.sq2  = (float*)take(NEXP * HDIM * 4);
  w.imp  = (float*)take(NEXP * 4);
  w.cnt  = (float*)take(NEXP * 4);
  w.tv   = (float*)take(4);
  w.zero_bytes = (size_t)((base + off) - w.zero_base);
  w.total = off;
  return w;
}

extern "C" void kernel_launch(void* const* d_in, const int* in_sizes, int n_in,
                              void* d_out, int out_size, void* d_ws, size_t ws_size,
                              hipStream_t stream)
{
  const float* v      = (const float*)d_in[0];
  const int*   a_rows = (const int*)d_in[1];
  const int*   a_cols = (const int*)d_in[2];
  const float* a_vals = (const float*)d_in[3];
  const float* gate_W = (const float*)d_in[4];
  const float* gate_b = (const float*)d_in[5];
  const float* eps    = (const float*)d_in[6];
  const float* W1     = (const float*)d_in[7];
  const float* g1     = (const float*)d_in[9];
  const float* beta1  = (const float*)d_in[10];
  const float* W2     = (const float*)d_in[11];
  const float* g2     = (const float*)d_in[13];
  const float* beta2  = (const float*)d_in[14];
  const int NE = in_sizes[1];
  float* out = (float*)d_out;
  (void)n_in; (void)out_size; (void)ws_size;

  WS w = carve_ws((char*)d_ws);

  hipMemsetAsync(w.zero_base, 0, w.zero_bytes, stream);

  const int nGat = NNODES / 64;                       // 800
  const int nBtc = (KC1 + KS2) * NEXP;                // 272
  const int nA   = (NE + EPB - 1) / EPB;              // 200
  prep_kernel<<<nGat + nBtc + nA, 256, 0, stream>>>(
      v, gate_W, gate_b, w.top_idx, w.top_val, w.v_bf, w.imp, w.cnt, w.tv,
      W1, W2, eps, w.Bt1x, w.Bt2,
      a_rows, a_cols, a_vals, w.bcnt, w.tmp, NE, nGat);

  bucketB_kernel<<<NB, 256, 0, stream>>>(
      w.tmp, w.bcnt, w.cv, w.row_start, w.counts);

  // aggregate split into two half-dispatches (instrumentation: lets the
  // next-slowest kernel surface in top-5; ~2.5 us overhead)
  aggregate_kernel<<<NNODES / 8, 256, 0, stream>>>(
      w.v_bf, w.cv, w.row_start, w.counts, w.agg_bf, 0);
  aggregate_kernel<<<NNODES / 8, 256, 0, stream>>>(
      w.v_bf, w.cv, w.row_start, w.counts, w.agg_bf, NNODES / 2);

  gemm1_mfma<<<NNODES / 64, 256, 0, stream>>>(
      w.agg_bf, w.v_bf, w.Bt1x, w.h1, w.sum1, w.sq1);
  gemm2_mfma<<<dim3(NBX2, NEXP), 256, 0, stream>>>(
      w.h1, w.Bt2, w.sum1, w.sq1, g1, beta1, w.top_idx,
      w.h2_sel, w.part2);
  reduce2_kernel<<<dim3(NEXP, 4), 256, 0, stream>>>(
      w.part2, w.sum2, w.sq2);
  combine_kernel<<<(NNODES * HDIM) / 1024, 256, 0, stream>>>(
      w.h2_sel, w.top_idx, w.top_val, w.sum2, w.sq2, g2, beta2,
      w.imp, w.cnt, w.tv, out);
}

// Round 12
// 462.933 us; speedup vs baseline: 1.0458x; 1.0080x over previous
//
#include <hip/hip_runtime.h>

// LayerGIN MoE — round 21: gating restructure (serial-depth cut + more blocks).
//  * Round-20: gemm2 atomic fix confirmed (-17.5 us, gemm2 left top-5).
//    New #2 = prep_kernel 85 us, all pipes idle (VALU 25%, Occ 29%) ->
//    latency-bound: gating's serial 16-node loop with 6-round shfl tree
//    (96 dependent rounds/wave) on a 1272-block grid (~5 blocks/CU).
//  * gating v2: 2 nodes per wave-iteration (half-wave x 25 lanes x 8 feat),
//    5-round half-wave reduce -> 20 dependent rounds/wave (4.8x less);
//    32 nodes/block -> nGat 800->1600; v_bf written as short8 (lane 25
//    zero-fills the 200..207 pad — feeds gemm1's zero-weighted columns).
//  * bucketA: EPB 8192->4096 (200->400 blocks) for tail parallelism.
//  * everything else byte-identical to round 20 (466.6 us measured).

#define NNODES 51200
#define CDIM   200
#define CPAD   208   // 416 B rows = exactly 7 cache lines at either 0/32 phase
#define HDIM   128
#define NEXP   8
#define BNEPS  1e-5f
#define KC1    26    // K=416 chunks of 16 for A'=[agg;v]
#define KS2    8     // 128/16
#define NB     400   // scatter buckets (128 rows each)
#define CAP    6144  // fixed bucket capacity (mean 4096, sigma 64)
#define EPB    4096  // edges per block, pass A
#define NBX2   400   // gemm2 grid.x = NNODES/128

typedef __attribute__((ext_vector_type(8)))  short short8;
typedef __attribute__((ext_vector_type(16))) float floatx16;
typedef unsigned short ushort_t;

__device__ __forceinline__ ushort_t f2bf(float x) {
  unsigned int u = __float_as_uint(x);
  u += 0x7fffu + ((u >> 16) & 1u);
  return (ushort_t)(u >> 16);
}
__device__ __forceinline__ float bf2f(ushort_t h) {
  return __uint_as_float(((unsigned int)h) << 16);
}

// ---- gating v2: 2 nodes per wave-iteration, half-wave feature ownership.
// Lanes l32=0..24 of each half own 8 features (c0=l32*8); 5-round shfl_xor
// reduce stays within the 32-lane half. 32 nodes per block (4 waves x 8).
__device__ void gating_body(
    int bid, const float* __restrict__ v, const float* __restrict__ gW,
    const float* __restrict__ gb, int* __restrict__ top_idx,
    float* __restrict__ top_val, ushort_t* __restrict__ v_bf,
    float* __restrict__ imp_acc, float* __restrict__ cnt_acc,
    float* __restrict__ tv_acc)
{
  __shared__ float s_imp[NEXP], s_cnt[NEXP], s_tv;
  const int tid = threadIdx.x, lane = tid & 63, wave = tid >> 6;
  if (tid < NEXP) { s_imp[tid] = 0.f; s_cnt[tid] = 0.f; }
  if (tid == 0) s_tv = 0.f;
  __syncthreads();
  const int l32 = lane & 31, half = lane >> 5;
  const int c0 = l32 * 8;
  const bool act = l32 < 25;               // 25 lanes x 8 features = 200
  float gwr[8][NEXP];
#pragma unroll
  for (int r = 0; r < 8; ++r) {
    float4 w0 = make_float4(0.f, 0.f, 0.f, 0.f);
    float4 w1 = make_float4(0.f, 0.f, 0.f, 0.f);
    if (act) {
      w0 = *(const float4*)(gW + (c0 + r) * NEXP);
      w1 = *(const float4*)(gW + (c0 + r) * NEXP + 4);
    }
    gwr[r][0] = w0.x; gwr[r][1] = w0.y; gwr[r][2] = w0.z; gwr[r][3] = w0.w;
    gwr[r][4] = w1.x; gwr[r][5] = w1.y; gwr[r][6] = w1.z; gwr[r][7] = w1.w;
  }
  float gbr[NEXP];
#pragma unroll
  for (int e = 0; e < NEXP; ++e) gbr[e] = gb[e];

#pragma unroll 1
  for (int i = 0; i < 4; ++i) {
    const int node = bid * 32 + wave * 8 + 2 * i + half;
    float4 x0 = make_float4(0.f, 0.f, 0.f, 0.f);
    float4 x1 = make_float4(0.f, 0.f, 0.f, 0.f);
    if (act) {
      x0 = *(const float4*)(v + (size_t)node * CDIM + c0);
      x1 = *(const float4*)(v + (size_t)node * CDIM + c0 + 4);
    }
    float p[NEXP];
#pragma unroll
    for (int e = 0; e < NEXP; ++e)
      p[e] = fmaf(x0.x, gwr[0][e],
             fmaf(x0.y, gwr[1][e],
             fmaf(x0.z, gwr[2][e],
             fmaf(x0.w, gwr[3][e],
             fmaf(x1.x, gwr[4][e],
             fmaf(x1.y, gwr[5][e],
             fmaf(x1.z, gwr[6][e], x1.w * gwr[7][e])))))));
#pragma unroll
    for (int off = 16; off > 0; off >>= 1)
#pragma unroll
      for (int e = 0; e < NEXP; ++e) p[e] += __shfl_xor(p[e], off, 64);
#pragma unroll
    for (int e = 0; e < NEXP; ++e) p[e] += gbr[e];
    // v_bf write: 16 B/lane; l32==25 zero-fills pad entries 200..207
    if (l32 < 26) {
      short8 o = {0, 0, 0, 0, 0, 0, 0, 0};
      if (act) {
        o[0] = (short)f2bf(x0.x); o[1] = (short)f2bf(x0.y);
        o[2] = (short)f2bf(x0.z); o[3] = (short)f2bf(x0.w);
        o[4] = (short)f2bf(x1.x); o[5] = (short)f2bf(x1.y);
        o[6] = (short)f2bf(x1.z); o[7] = (short)f2bf(x1.w);
      }
      *(short8*)(v_bf + (size_t)node * CPAD + c0) = o;
    }
    float mx = p[0]; int ai = 0;
#pragma unroll
    for (int e = 1; e < NEXP; ++e) if (p[e] > mx) { mx = p[e]; ai = e; }
    float se = 0.f, pe[NEXP];
#pragma unroll
    for (int e = 0; e < NEXP; ++e) { pe[e] = __expf(p[e] - mx); se += pe[e]; }
    const float inv = 1.f / se;
    if (l32 == 0) {
      top_idx[node] = ai;
      top_val[node] = inv;
#pragma unroll
      for (int e = 0; e < NEXP; ++e) atomicAdd(&s_imp[e], pe[e] * inv);
      atomicAdd(&s_cnt[ai], 1.f);
      atomicAdd(&s_tv, inv);
    }
  }
  __syncthreads();
  if (tid < NEXP) { atomicAdd(&imp_acc[tid], s_imp[tid]); atomicAdd(&cnt_acc[tid], s_cnt[tid]); }
  if (tid == 0) atomicAdd(tv_acc, s_tv);
}

// -------------------- weight prep body: W1 stacked [W1;se*W1] + W2 plain
__device__ void btconv_body(
    int j, int e, const float* __restrict__ W1, const float* __restrict__ W2,
    const float* __restrict__ eps, ushort_t* __restrict__ Bt1,
    ushort_t* __restrict__ Bt2)
{
  __shared__ float tile[16][128];
  const int tid = threadIdx.x;
  const int kr = tid >> 5, n4 = (tid & 31) * 4;
  const float* W; int K, jj; float sc; ushort_t* dst;
  if (j < KC1) {
    sc = (j >= 13) ? (1.f + eps[e]) : 1.f;
    jj = (j >= 13) ? (j - 13) : j;
    W = W1; K = CDIM;
    dst = Bt1 + (((size_t)e * KC1 + j) * 256) * 8;
  } else {
    sc = 1.f; jj = j - KC1; W = W2; K = HDIM;
    dst = Bt2 + (((size_t)e * KS2 + jj) * 256) * 8;
  }
#pragma unroll
  for (int h = 0; h < 2; ++h) {
    const int k = jj * 16 + kr + h * 8;
    float4 val = make_float4(0.f, 0.f, 0.f, 0.f);
    if (k < K) val = *(const float4*)(W + ((size_t)e * K + k) * HDIM + n4);
    *(float4*)&tile[kr + h * 8][n4] = val;
  }
  __syncthreads();
  const int kh = tid >> 7, n = tid & 127;
  short8 pk;
#pragma unroll
  for (int q = 0; q < 8; ++q) pk[q] = (short)f2bf(sc * tile[kh * 8 + q][n]);
  *(short8*)(dst + (size_t)tid * 8) = pk;
}

// ---- pass A body: coarse bucket scatter into fixed-capacity bucket slots ----
__device__ void bucketA_body(
    int bid, const int* __restrict__ rows, const int* __restrict__ cols,
    const float* __restrict__ vals, int* __restrict__ bcnt,
    int2* __restrict__ tmp, int ne)
{
  __shared__ int cnt[NB];
  __shared__ int gbase[NB];
  const int tid = threadIdx.x;
  const int base = bid * EPB;
  for (int b = tid; b < NB; b += 256) cnt[b] = 0;
  __syncthreads();
#pragma unroll 4
  for (int j = 0; j < EPB / 256; ++j) {
    const int i = base + j * 256 + tid;
    if (i < ne) atomicAdd(&cnt[rows[i] >> 7], 1);
  }
  __syncthreads();
  for (int b = tid; b < NB; b += 256) {
    const int c = cnt[b];
    gbase[b] = c ? (b * CAP + atomicAdd(&bcnt[b], c)) : 0;
    cnt[b] = 0;
  }
  __syncthreads();
#pragma unroll 4
  for (int j = 0; j < EPB / 256; ++j) {
    const int i = base + j * 256 + tid;
    if (i < ne) {
      const int r = rows[i];
      const int b = r >> 7;
      const int pos = gbase[b] + atomicAdd(&cnt[b], 1);
      tmp[pos] = make_int2((r << 16) | cols[i], __float_as_int(vals[i]));
    }
  }
}

// ---- merged front-end: [gating nGat | btconv 272 | bucketA nA] ----
__global__ __launch_bounds__(256) void prep_kernel(
    const float* __restrict__ v, const float* __restrict__ gW,
    const float* __restrict__ gb, int* __restrict__ top_idx,
    float* __restrict__ top_val, ushort_t* __restrict__ v_bf,
    float* __restrict__ imp_acc, float* __restrict__ cnt_acc,
    float* __restrict__ tv_acc,
    const float* __restrict__ W1, const float* __restrict__ W2,
    const float* __restrict__ eps, ushort_t* __restrict__ Bt1,
    ushort_t* __restrict__ Bt2,
    const int* __restrict__ rows, const int* __restrict__ cols,
    const float* __restrict__ vals, int* __restrict__ bcnt,
    int2* __restrict__ tmp, int ne, int nGat)
{
  const int bid = blockIdx.x;
  if (bid < nGat) {
    gating_body(bid, v, gW, gb, top_idx, top_val, v_bf, imp_acc, cnt_acc, tv_acc);
  } else if (bid < nGat + (KC1 + KS2) * NEXP) {
    const int b2 = bid - nGat;
    btconv_body(b2 % (KC1 + KS2), b2 / (KC1 + KS2), W1, W2, eps, Bt1, Bt2);
  } else {
    bucketA_body(bid - nGat - (KC1 + KS2) * NEXP, rows, cols, vals, bcnt, tmp, ne);
  }
}

// ---- pass B: register-resident bucket; local hist+scan -> row_start/counts,
//      then LDS-cursor scatter into cv
__global__ __launch_bounds__(256) void bucketB_kernel(
    const int2* __restrict__ tmp, const int* __restrict__ bcnt,
    int2* __restrict__ cv, int* __restrict__ row_start, int* __restrict__ counts)
{
  __shared__ int lhist[128];
  __shared__ int lcur[128];
  const int tid = threadIdx.x;
  const int b = blockIdx.x;
  const int n = bcnt[b];
  const int base = b * CAP;
  int2 ed[CAP / 256];
#pragma unroll
  for (int j = 0; j < CAP / 256; ++j) {
    const int i = j * 256 + tid;
    if (i < n) ed[j] = tmp[base + i];
  }
  if (tid < 128) lhist[tid] = 0;
  __syncthreads();
#pragma unroll
  for (int j = 0; j < CAP / 256; ++j)
    if (j * 256 + tid < n)
      atomicAdd(&lhist[(((unsigned)ed[j].x) >> 16) & 127], 1);
  __syncthreads();
  if (tid == 0) {
    int acc = base;
    for (int r = 0; r < 128; ++r) { lcur[r] = acc; acc += lhist[r]; }
  }
  __syncthreads();
  if (tid < 128) {
    row_start[(b << 7) + tid] = lcur[tid];
    counts[(b << 7) + tid] = lhist[tid];
  }
  __syncthreads();
#pragma unroll
  for (int j = 0; j < CAP / 256; ++j)
    if (j * 256 + tid < n) {
      const int r = (((unsigned)ed[j].x) >> 16) & 127;
      const int pos = atomicAdd(&lcur[r], 1);
      cv[pos] = make_int2(ed[j].x & 0xffff, ed[j].y);
    }
}

// aggregate v4: one wave per destination node, 2 edges per gather instruction,
// lane-distributed edge prefetch. node0 = node-range offset (split dispatch).
__global__ __launch_bounds__(256) void aggregate_kernel(
    const ushort_t* __restrict__ v_bf, const int2* __restrict__ cv,
    const int* __restrict__ row_start, const int* __restrict__ counts,
    ushort_t* __restrict__ agg_bf, int node0)
{
  const int node = node0 + ((blockIdx.x * 256 + threadIdx.x) >> 6);
  const int lane = threadIdx.x & 63;
  const int half = lane >> 5;
  const int l32  = lane & 31;
  const bool act = l32 < 26;                // 26 lanes x 8 elems = 208
  const int start = row_start[node];
  const int cnt   = counts[node];

  float acc[8];
#pragma unroll
  for (int j = 0; j < 8; ++j) acc[j] = 0.f;

  int ecol = 0, eval = 0;
  if (lane < cnt) {
    const int2 e = cv[start + lane];
    ecol = e.x; eval = e.y;
  }
  const int n64 = cnt < 64 ? cnt : 64;
  int k = 0;

  for (; k + 16 <= n64; k += 16) {
    short8 xx[8];
#pragma unroll
    for (int u = 0; u < 8; ++u) {
      const int cc = __shfl(ecol, k + 2 * u + half, 64);
      short8 t = {0, 0, 0, 0, 0, 0, 0, 0};
      if (act) t = *(const short8*)(v_bf + (size_t)cc * CPAD + l32 * 8);
      xx[u] = t;
    }
#pragma unroll
    for (int u = 0; u < 8; ++u) {
      const float vv = __int_as_float(__shfl(eval, k + 2 * u + half, 64));
#pragma unroll
      for (int j = 0; j < 8; ++j)
        acc[j] = fmaf(vv, bf2f((ushort_t)xx[u][j]), acc[j]);
    }
  }
  for (; k + 4 <= n64; k += 4) {
    short8 xx[2];
#pragma unroll
    for (int u = 0; u < 2; ++u) {
      const int cc = __shfl(ecol, k + 2 * u + half, 64);
      short8 t = {0, 0, 0, 0, 0, 0, 0, 0};
      if (act) t = *(const short8*)(v_bf + (size_t)cc * CPAD + l32 * 8);
      xx[u] = t;
    }
#pragma unroll
    for (int u = 0; u < 2; ++u) {
      const float vv = __int_as_float(__shfl(eval, k + 2 * u + half, 64));
#pragma unroll
      for (int j = 0; j < 8; ++j)
        acc[j] = fmaf(vv, bf2f((ushort_t)xx[u][j]), acc[j]);
    }
  }
  for (; k < n64; k += 2) {
    const int idx = k + half;
    const int cc = __shfl(ecol, idx, 64);
    short8 t = {0, 0, 0, 0, 0, 0, 0, 0};
    if (act) t = *(const short8*)(v_bf + (size_t)cc * CPAD + l32 * 8);
    const float vv = __int_as_float(__shfl(eval, idx, 64));
#pragma unroll
    for (int j = 0; j < 8; ++j)
      acc[j] = fmaf(vv, bf2f((ushort_t)t[j]), acc[j]);
  }
  for (; k < cnt; ++k) {
    const int2 e0 = cv[start + k];
    short8 x0 = {0, 0, 0, 0, 0, 0, 0, 0};
    if (act && half == 0)
      x0 = *(const short8*)(v_bf + (size_t)e0.x * CPAD + l32 * 8);
    const float v0 = half ? 0.f : __int_as_float(e0.y);
#pragma unroll
    for (int j = 0; j < 8; ++j)
      acc[j] = fmaf(v0, bf2f((ushort_t)x0[j]), acc[j]);
  }

#pragma unroll
  for (int j = 0; j < 8; ++j) acc[j] += __shfl_xor(acc[j], 32, 64);

  if (act && half == 0) {
    short8 o;
#pragma unroll
    for (int j = 0; j < 8; ++j) o[j] = (short)f2bf(acc[j]);
    *(short8*)(agg_bf + (size_t)node * CPAD + l32 * 8) = o;
  }
}

// ---------------------------------------------- GEMM 1: occupancy-split
// acc[2][2] (64 AGPR) + ~70 VGPR => 3 blocks/CU at __launch_bounds__(256,3)
// (LDS caps at 3x53 KB = 159/160 KB). Each wave: 4 serial (e, N-half) tasks.
__global__ __launch_bounds__(256, 3) void gemm1_mfma(
    const ushort_t* __restrict__ agg_bf, const ushort_t* __restrict__ v_bf,
    const ushort_t* __restrict__ Bt1x, ushort_t* __restrict__ h1,
    float* __restrict__ sum1, float* __restrict__ sq1)
{
  const int m0 = blockIdx.x * 64;
  __shared__ ushort_t sA[52 * 64 * 8];       // 53248 B
  const int tid = threadIdx.x;
  const int lane = tid & 63, wid = tid >> 6;
  const int l31 = lane & 31, half = lane >> 5;

#pragma unroll
  for (int it = 0; it < 13; ++it) {
    const int l = it * 256 + tid;
    const int g = l >> 6, m = l & 63;
    const ushort_t* src = (g < 26)
        ? agg_bf + (size_t)(m0 + m) * CPAD + g * 8
        : v_bf  + (size_t)(m0 + m) * CPAD + (g - 26) * 8;
    *(short8*)(sA + (size_t)l * 8) = *(const short8*)src;
  }
  __syncthreads();

#pragma unroll 1
  for (int t = 0; t < 4; ++t) {
    const int e  = wid + (t >> 1) * 4;     // t=0,1 -> e=wid; t=2,3 -> e=wid+4
    const int nh = t & 1;
    floatx16 acc[2][2];
#pragma unroll
    for (int ms = 0; ms < 2; ++ms)
#pragma unroll
      for (int ns = 0; ns < 2; ++ns)
#pragma unroll
        for (int r = 0; r < 16; ++r) acc[ms][ns][r] = 0.f;

    const ushort_t* bte =
        Bt1x + ((size_t)e * KC1 * 256 + half * 128 + nh * 64 + l31) * 8;
    short8 nb0 = *(const short8*)(bte);
    short8 nb1 = *(const short8*)(bte + 32 * 8);
#pragma unroll
    for (int j = 0; j < KC1; ++j) {
      const short8 b0 = nb0, b1 = nb1;
      if (j < KC1 - 1) {
        nb0 = *(const short8*)(bte + (size_t)((j + 1) * 256) * 8);
        nb1 = *(const short8*)(bte + (size_t)((j + 1) * 256 + 32) * 8);
      }
      const short8 a0 = *(const short8*)(sA + (size_t)((2 * j + half) * 64 + l31) * 8);
      const short8 a1 = *(const short8*)(sA + (size_t)((2 * j + half) * 64 + 32 + l31) * 8);
      acc[0][0] = __builtin_amdgcn_mfma_f32_32x32x16_bf16(a0, b0, acc[0][0], 0, 0, 0);
      acc[0][1] = __builtin_amdgcn_mfma_f32_32x32x16_bf16(a0, b1, acc[0][1], 0, 0, 0);
      acc[1][0] = __builtin_amdgcn_mfma_f32_32x32x16_bf16(a1, b0, acc[1][0], 0, 0, 0);
      acc[1][1] = __builtin_amdgcn_mfma_f32_32x32x16_bf16(a1, b1, acc[1][1], 0, 0, 0);
    }

    ushort_t* h1e = h1 + ((size_t)e * NNODES + m0) * HDIM;
#pragma unroll
    for (int ns = 0; ns < 2; ++ns) {
      const int col = nh * 64 + ns * 32 + l31;
      float s = 0.f, q = 0.f;
#pragma unroll
      for (int ms = 0; ms < 2; ++ms) {
#pragma unroll
        for (int r = 0; r < 16; ++r) {
          const int row = ms * 32 + (r & 3) + 8 * (r >> 2) + 4 * half;
          const float x = acc[ms][ns][r];
          h1e[(size_t)row * HDIM + col] = f2bf(x);
          s += x; q = fmaf(x, x, q);
        }
      }
      s += __shfl_xor(s, 32, 64);
      q += __shfl_xor(q, 32, 64);
      if (half == 0) {
        atomicAdd(&sum1[e * HDIM + col], s);
        atomicAdd(&sq1[e * HDIM + col], q);
      }
    }
  }
}

// ------------- GEMM 2: BN1 finalize in prologue + single-barrier A staging.
// Global atomics replaced by per-block partial stores (part2) — round-20.
__global__ __launch_bounds__(256, 4) void gemm2_mfma(
    const ushort_t* __restrict__ h1, const ushort_t* __restrict__ Bt2,
    const float* __restrict__ sum1, const float* __restrict__ sq1,
    const float* __restrict__ g1, const float* __restrict__ beta1,
    const int* __restrict__ top_idx, float* __restrict__ h2_sel,
    float* __restrict__ part2)
{
  const int e = blockIdx.y;
  const int m0 = blockIdx.x * 128;
  __shared__ ushort_t sA[16 * 129 * 8];     // 33024 B
  __shared__ float ssum[HDIM], ssq[HDIM];
  __shared__ float sSc[HDIM], sSh[HDIM];
  __shared__ int sTop[128];
  const int tid = threadIdx.x;
  const int lane = tid & 63, wid = tid >> 6;
  const int wm = wid >> 1, wn = wid & 1;
  const int l31 = lane & 31, half = lane >> 5;
  if (tid < HDIM) {
    ssum[tid] = 0.f; ssq[tid] = 0.f;
    sTop[tid] = top_idx[m0 + tid];
    const int i = e * HDIM + tid;
    const float invN = 1.f / (float)NNODES;
    const float mean = sum1[i] * invN;
    const float var  = sq1[i] * invN - mean * mean;
    const float sc = rsqrtf(var + BNEPS) * g1[i];
    sSc[tid] = sc;
    sSh[tid] = fmaf(-mean, sc, beta1[i]);
  }
  __syncthreads();
  {
    const int g = tid & 15, r0 = tid >> 4;
    const float4 sc0 = *(const float4*)&sSc[g * 8];
    const float4 sc1 = *(const float4*)&sSc[g * 8 + 4];
    const float4 sh0 = *(const float4*)&sSh[g * 8];
    const float4 sh1 = *(const float4*)&sSh[g * 8 + 4];
#pragma unroll
    for (int c = 0; c < 8; ++c) {
      const int m = c * 16 + r0;
      const short8 hq = *(const short8*)(
          h1 + ((size_t)e * NNODES + m0 + m) * HDIM + g * 8);
      short8 pk;
      pk[0] = (short)f2bf(fmaxf(0.f, fmaf(bf2f((ushort_t)hq[0]), sc0.x, sh0.x)));
      pk[1] = (short)f2bf(fmaxf(0.f, fmaf(bf2f((ushort_t)hq[1]), sc0.y, sh0.y)));
      pk[2] = (short)f2bf(fmaxf(0.f, fmaf(bf2f((ushort_t)hq[2]), sc0.z, sh0.z)));
      pk[3] = (short)f2bf(fmaxf(0.f, fmaf(bf2f((ushort_t)hq[3]), sc0.w, sh0.w)));
      pk[4] = (short)f2bf(fmaxf(0.f, fmaf(bf2f((ushort_t)hq[4]), sc1.x, sh1.x)));
      pk[5] = (short)f2bf(fmaxf(0.f, fmaf(bf2f((ushort_t)hq[5]), sc1.y, sh1.y)));
      pk[6] = (short)f2bf(fmaxf(0.f, fmaf(bf2f((ushort_t)hq[6]), sc1.z, sh1.z)));
      pk[7] = (short)f2bf(fmaxf(0.f, fmaf(bf2f((ushort_t)hq[7]), sc1.w, sh1.w)));
      *(short8*)(sA + (size_t)(g * 129 + m) * 8) = pk;
    }
  }
  __syncthreads();

  floatx16 acc[2][2];
#pragma unroll
  for (int i = 0; i < 2; ++i)
#pragma unroll
    for (int j = 0; j < 2; ++j)
#pragma unroll
      for (int r = 0; r < 16; ++r) acc[i][j][r] = 0.f;

  const ushort_t* bte = Bt2 + ((size_t)e * KS2 * 256 + half * 128 + wn * 64 + l31) * 8;
  short8 nb0 = *(const short8*)(bte);
  short8 nb1 = *(const short8*)(bte + 32 * 8);
#pragma unroll
  for (int ks = 0; ks < KS2; ++ks) {
    const short8 b0 = nb0, b1 = nb1;
    if (ks < KS2 - 1) {
      nb0 = *(const short8*)(bte + (size_t)((ks + 1) * 256) * 8);
      nb1 = *(const short8*)(bte + (size_t)((ks + 1) * 256 + 32) * 8);
    }
    const short8 a0 = *(const short8*)(sA + (size_t)((2 * ks + half) * 129 + wm * 64 + l31) * 8);
    const short8 a1 = *(const short8*)(sA + (size_t)((2 * ks + half) * 129 + wm * 64 + 32 + l31) * 8);
    acc[0][0] = __builtin_amdgcn_mfma_f32_32x32x16_bf16(a0, b0, acc[0][0], 0, 0, 0);
    acc[0][1] = __builtin_amdgcn_mfma_f32_32x32x16_bf16(a0, b1, acc[0][1], 0, 0, 0);
    acc[1][0] = __builtin_amdgcn_mfma_f32_32x32x16_bf16(a1, b0, acc[1][0], 0, 0, 0);
    acc[1][1] = __builtin_amdgcn_mfma_f32_32x32x16_bf16(a1, b1, acc[1][1], 0, 0, 0);
  }

#pragma unroll
  for (int ms = 0; ms < 2; ++ms)
#pragma unroll
    for (int ns = 0; ns < 2; ++ns) {
      const int col = wn * 64 + ns * 32 + l31;
      float s = 0.f, q = 0.f;
#pragma unroll
      for (int r = 0; r < 16; ++r) {
        const int row = wm * 64 + ms * 32 + (r & 3) + 8 * (r >> 2) + 4 * half;
        const float x = acc[ms][ns][r];
        if (sTop[row] == e) h2_sel[(size_t)(m0 + row) * HDIM + col] = x;
        s += x; q = fmaf(x, x, q);
      }
      atomicAdd(&ssum[col], s);
      atomicAdd(&ssq[col], q);
    }
  __syncthreads();
  // non-atomic coalesced partial store: [e][bx][0:128]=sum, [128:256]=sq
  part2[((size_t)(e * NBX2 + blockIdx.x)) * 256 + tid] =
      (tid < HDIM) ? ssum[tid] : ssq[tid - HDIM];
}

// ---- reduce2: sum part2 over the 400 gemm2 blocks -> sum2/sq2 (memset'd).
__global__ __launch_bounds__(256) void reduce2_kernel(
    const float* __restrict__ part2, float* __restrict__ sum2,
    float* __restrict__ sq2)
{
  const int e = blockIdx.x, q = blockIdx.y, tid = threadIdx.x;
  const float* base = part2 + ((size_t)(e * NBX2 + q * (NBX2 / 4))) * 256 + tid;
  float a0 = 0.f, a1 = 0.f, a2 = 0.f, a3 = 0.f;
#pragma unroll 1
  for (int b = 0; b < NBX2 / 4; b += 4) {
    a0 += base[(size_t)(b + 0) * 256];
    a1 += base[(size_t)(b + 1) * 256];
    a2 += base[(size_t)(b + 2) * 256];
    a3 += base[(size_t)(b + 3) * 256];
  }
  const float acc = (a0 + a1) + (a2 + a3);
  if (tid < HDIM) atomicAdd(&sum2[e * HDIM + tid], acc);
  else            atomicAdd(&sq2[e * HDIM + tid - HDIM], acc);
}

// --------------------- combine: BN2 finalize in prologue + gate + aux losses
__global__ __launch_bounds__(256) void combine_kernel(
    const float* __restrict__ h2_sel, const int* __restrict__ top_idx,
    const float* __restrict__ top_val, const float* __restrict__ sum2,
    const float* __restrict__ sq2, const float* __restrict__ g2,
    const float* __restrict__ beta2, const float* __restrict__ imp,
    const float* __restrict__ cntv, const float* __restrict__ tv,
    float* __restrict__ out)
{
  __shared__ float s2[NEXP * HDIM], b2s[NEXP * HDIM];
  const int tid = threadIdx.x;
  const float invN = 1.f / (float)NNODES;
  for (int t = tid; t < NEXP * HDIM; t += 256) {
    const float mean = sum2[t] * invN;
    const float var  = sq2[t] * invN - mean * mean;
    const float sc = rsqrtf(var + BNEPS) * g2[t];
    s2[t] = sc;
    b2s[t] = fmaf(-mean, sc, beta2[t]);
  }
  __syncthreads();
  const int i4 = (blockIdx.x * 256 + tid) * 4;
  const int n = i4 >> 7, h = i4 & 127;
  const int e = top_idx[n];
  const float tvv = top_val[n];
  const float4 x = *(const float4*)(h2_sel + i4);
  const float* sc = s2 + e * HDIM + h;
  const float* sh = b2s + e * HDIM + h;
  float4 o;
  o.x = tvv * fmaxf(0.f, fmaf(x.x, sc[0], sh[0]));
  o.y = tvv * fmaxf(0.f, fmaf(x.y, sc[1], sh[1]));
  o.z = tvv * fmaxf(0.f, fmaf(x.z, sc[2], sh[2]));
  o.w = tvv * fmaxf(0.f, fmaf(x.w, sc[3], sh[3]));
  *(float4*)(out + i4) = o;
  if (blockIdx.x == 0 && tid == 0) {
    float bal = 0.f;
#pragma unroll
    for (int q = 0; q < NEXP; ++q) bal += (imp[q] * invN) * (cntv[q] * invN);
    out[(size_t)NNODES * HDIM]     = 0.01f * (float)NEXP * bal;
    out[(size_t)NNODES * HDIM + 1] = -0.01f * tv[0] * invN;
  }
}

// ----------------------------------------------------------------- launch
struct WS {
  ushort_t *v_bf, *agg_bf, *h1, *Bt1x, *Bt2;
  float *h2_sel, *part2;
  int2 *cv, *tmp;
  int *row_start, *counts, *top_idx;
  float *top_val;
  char *zero_base; size_t zero_bytes;
  int *bcnt;
  float *sum1, *sq1, *sum2, *sq2, *imp, *cnt, *tv;
  size_t total;
};

static WS carve_ws(char* base)
{
  WS w; size_t off = 0;
  auto take = [&](size_t b) -> char* {
    char* r = base + off; off += (b + 255) & ~(size_t)255; return r;
  };
  // v_bf (21.3 MB) + agg_bf (21.3 MB) adjacent; h2_sel alias (26.2 MB f32)
  // spills from v_bf into agg_bf, which is dead after gemm1.
  w.v_bf   = (ushort_t*)take((size_t)NNODES * CPAD * 2);
  w.agg_bf = (ushort_t*)take((size_t)NNODES * CPAD * 2);
  w.h2_sel = (float*)w.v_bf;
  w.h1     = (ushort_t*)take((size_t)NEXP * NNODES * HDIM * 2);
  w.cv     = (int2*)take((size_t)NB * CAP * 8);
  w.tmp    = (int2*)take((size_t)NB * CAP * 8);
  w.Bt1x   = (ushort_t*)take((size_t)NEXP * KC1 * 2048 * 2);
  w.Bt2    = (ushort_t*)take((size_t)NEXP * KS2 * 2048 * 2);
  w.part2  = (float*)take((size_t)NEXP * NBX2 * 256 * 4);   // 3.3 MB, fully written
  w.row_start = (int*)take(NNODES * 4);
  w.counts    = (int*)take(NNODES * 4);
  w.top_idx   = (int*)take(NNODES * 4);
  w.top_val   = (float*)take(NNODES * 4);
  w.zero_base = base + off;
  w.bcnt = (int*)take(NB * 4);
  w.sum1 = (float*)take(NEXP * HDIM * 4);
  w.sq1  = (float*)take(NEXP * HDIM * 4);
  w.sum2 = (float*)take(NEXP * HDIM * 4);
  w.sq2  = (float*)take(NEXP * HDIM * 4);
  w.imp  = (float*)take(NEXP * 4);
  w.cnt  = (float*)take(NEXP * 4);
  w.tv   = (float*)take(4);
  w.zero_bytes = (size_t)((base + off) - w.zero_base);
  w.total = off;
  return w;
}

extern "C" void kernel_launch(void* const* d_in, const int* in_sizes, int n_in,
                              void* d_out, int out_size, void* d_ws, size_t ws_size,
                              hipStream_t stream)
{
  const float* v      = (const float*)d_in[0];
  const int*   a_rows = (const int*)d_in[1];
  const int*   a_cols = (const int*)d_in[2];
  const float* a_vals = (const float*)d_in[3];
  const float* gate_W = (const float*)d_in[4];
  const float* gate_b = (const float*)d_in[5];
  const float* eps    = (const float*)d_in[6];
  const float* W1     = (const float*)d_in[7];
  const float* g1     = (const float*)d_in[9];
  const float* beta1  = (const float*)d_in[10];
  const float* W2     = (const float*)d_in[11];
  const float* g2     = (const float*)d_in[13];
  const float* beta2  = (const float*)d_in[14];
  const int NE = in_sizes[1];
  float* out = (float*)d_out;
  (void)n_in; (void)out_size; (void)ws_size;

  WS w = carve_ws((char*)d_ws);

  hipMemsetAsync(w.zero_base, 0, w.zero_bytes, stream);

  const int nGat = NNODES / 32;                       // 1600
  const int nBtc = (KC1 + KS2) * NEXP;                // 272
  const int nA   = (NE + EPB - 1) / EPB;              // 400
  prep_kernel<<<nGat + nBtc + nA, 256, 0, stream>>>(
      v, gate_W, gate_b, w.top_idx, w.top_val, w.v_bf, w.imp, w.cnt, w.tv,
      W1, W2, eps, w.Bt1x, w.Bt2,
      a_rows, a_cols, a_vals, w.bcnt, w.tmp, NE, nGat);

  bucketB_kernel<<<NB, 256, 0, stream>>>(
      w.tmp, w.bcnt, w.cv, w.row_start, w.counts);

  // aggregate split into two half-dispatches (instrumentation: lets the
  // next-slowest kernel surface in top-5; ~2.5 us overhead)
  aggregate_kernel<<<NNODES / 8, 256, 0, stream>>>(
      w.v_bf, w.cv, w.row_start, w.counts, w.agg_bf, 0);
  aggregate_kernel<<<NNODES / 8, 256, 0, stream>>>(
      w.v_bf, w.cv, w.row_start, w.counts, w.agg_bf, NNODES / 2);

  gemm1_mfma<<<NNODES / 64, 256, 0, stream>>>(
      w.agg_bf, w.v_bf, w.Bt1x, w.h1, w.sum1, w.sq1);
  gemm2_mfma<<<dim3(NBX2, NEXP), 256, 0, stream>>>(
      w.h1, w.Bt2, w.sum1, w.sq1, g1, beta1, w.top_idx,
      w.h2_sel, w.part2);
  reduce2_kernel<<<dim3(NEXP, 4), 256, 0, stream>>>(
      w.part2, w.sum2, w.sq2);
  combine_kernel<<<(NNODES * HDIM) / 1024, 256, 0, stream>>>(
      w.h2_sel, w.top_idx, w.top_val, w.sum2, w.sq2, g2, beta2,
      w.imp, w.cnt, w.tv, out);
}

// Round 13
// 460.803 us; speedup vs baseline: 1.0506x; 1.0046x over previous
//
#include <hip/hip_runtime.h>

// LayerGIN MoE — round 22: gemm1 de-atomicization + distance-2 B prefetch.
//  * Round-21: gating restructure ~null (-3.7 us) — prep's cost wasn't the
//    shfl tree. gemm1 surfaced: 85 us, Mfma 20%, Occ 23%, all pipes idle.
//  * gemm1 has the SAME disease fixed in gemm2 (round-20, -40 us): 819K
//    device atomics into 128 lines of sum1/sq1. Fix identically: per-block
//    partial stores part1[e][bx][256] (non-atomic — each (e,col) owned by
//    one wave per block) + reduce1_kernel (8x16 grid, coalesced, 16-way
//    trivial atomics into memset'd sum1/sq1).
//  * gemm1 K-loop: distance-2 B prefetch (L2 ~200cyc vs ~55cyc body at only
//    3 waves/SIMD; distance-1 didn't cover). +16 VGPR -> ~100, same bucket.
//  * everything else byte-identical to round 21 (462.9 us measured).

#define NNODES 51200
#define CDIM   200
#define CPAD   208   // 416 B rows = exactly 7 cache lines at either 0/32 phase
#define HDIM   128
#define NEXP   8
#define BNEPS  1e-5f
#define KC1    26    // K=416 chunks of 16 for A'=[agg;v]
#define KS2    8     // 128/16
#define NB     400   // scatter buckets (128 rows each)
#define CAP    6144  // fixed bucket capacity (mean 4096, sigma 64)
#define EPB    4096  // edges per block, pass A
#define NBX2   400   // gemm2 grid.x = NNODES/128
#define NBLK1  800   // gemm1 grid.x = NNODES/64

typedef __attribute__((ext_vector_type(8)))  short short8;
typedef __attribute__((ext_vector_type(16))) float floatx16;
typedef unsigned short ushort_t;

__device__ __forceinline__ ushort_t f2bf(float x) {
  unsigned int u = __float_as_uint(x);
  u += 0x7fffu + ((u >> 16) & 1u);
  return (ushort_t)(u >> 16);
}
__device__ __forceinline__ float bf2f(ushort_t h) {
  return __uint_as_float(((unsigned int)h) << 16);
}

// ---- gating v2: 2 nodes per wave-iteration, half-wave feature ownership.
__device__ void gating_body(
    int bid, const float* __restrict__ v, const float* __restrict__ gW,
    const float* __restrict__ gb, int* __restrict__ top_idx,
    float* __restrict__ top_val, ushort_t* __restrict__ v_bf,
    float* __restrict__ imp_acc, float* __restrict__ cnt_acc,
    float* __restrict__ tv_acc)
{
  __shared__ float s_imp[NEXP], s_cnt[NEXP], s_tv;
  const int tid = threadIdx.x, lane = tid & 63, wave = tid >> 6;
  if (tid < NEXP) { s_imp[tid] = 0.f; s_cnt[tid] = 0.f; }
  if (tid == 0) s_tv = 0.f;
  __syncthreads();
  const int l32 = lane & 31, half = lane >> 5;
  const int c0 = l32 * 8;
  const bool act = l32 < 25;               // 25 lanes x 8 features = 200
  float gwr[8][NEXP];
#pragma unroll
  for (int r = 0; r < 8; ++r) {
    float4 w0 = make_float4(0.f, 0.f, 0.f, 0.f);
    float4 w1 = make_float4(0.f, 0.f, 0.f, 0.f);
    if (act) {
      w0 = *(const float4*)(gW + (c0 + r) * NEXP);
      w1 = *(const float4*)(gW + (c0 + r) * NEXP + 4);
    }
    gwr[r][0] = w0.x; gwr[r][1] = w0.y; gwr[r][2] = w0.z; gwr[r][3] = w0.w;
    gwr[r][4] = w1.x; gwr[r][5] = w1.y; gwr[r][6] = w1.z; gwr[r][7] = w1.w;
  }
  float gbr[NEXP];
#pragma unroll
  for (int e = 0; e < NEXP; ++e) gbr[e] = gb[e];

#pragma unroll 1
  for (int i = 0; i < 4; ++i) {
    const int node = bid * 32 + wave * 8 + 2 * i + half;
    float4 x0 = make_float4(0.f, 0.f, 0.f, 0.f);
    float4 x1 = make_float4(0.f, 0.f, 0.f, 0.f);
    if (act) {
      x0 = *(const float4*)(v + (size_t)node * CDIM + c0);
      x1 = *(const float4*)(v + (size_t)node * CDIM + c0 + 4);
    }
    float p[NEXP];
#pragma unroll
    for (int e = 0; e < NEXP; ++e)
      p[e] = fmaf(x0.x, gwr[0][e],
             fmaf(x0.y, gwr[1][e],
             fmaf(x0.z, gwr[2][e],
             fmaf(x0.w, gwr[3][e],
             fmaf(x1.x, gwr[4][e],
             fmaf(x1.y, gwr[5][e],
             fmaf(x1.z, gwr[6][e], x1.w * gwr[7][e])))))));
#pragma unroll
    for (int off = 16; off > 0; off >>= 1)
#pragma unroll
      for (int e = 0; e < NEXP; ++e) p[e] += __shfl_xor(p[e], off, 64);
#pragma unroll
    for (int e = 0; e < NEXP; ++e) p[e] += gbr[e];
    if (l32 < 26) {
      short8 o = {0, 0, 0, 0, 0, 0, 0, 0};
      if (act) {
        o[0] = (short)f2bf(x0.x); o[1] = (short)f2bf(x0.y);
        o[2] = (short)f2bf(x0.z); o[3] = (short)f2bf(x0.w);
        o[4] = (short)f2bf(x1.x); o[5] = (short)f2bf(x1.y);
        o[6] = (short)f2bf(x1.z); o[7] = (short)f2bf(x1.w);
      }
      *(short8*)(v_bf + (size_t)node * CPAD + c0) = o;
    }
    float mx = p[0]; int ai = 0;
#pragma unroll
    for (int e = 1; e < NEXP; ++e) if (p[e] > mx) { mx = p[e]; ai = e; }
    float se = 0.f, pe[NEXP];
#pragma unroll
    for (int e = 0; e < NEXP; ++e) { pe[e] = __expf(p[e] - mx); se += pe[e]; }
    const float inv = 1.f / se;
    if (l32 == 0) {
      top_idx[node] = ai;
      top_val[node] = inv;
#pragma unroll
      for (int e = 0; e < NEXP; ++e) atomicAdd(&s_imp[e], pe[e] * inv);
      atomicAdd(&s_cnt[ai], 1.f);
      atomicAdd(&s_tv, inv);
    }
  }
  __syncthreads();
  if (tid < NEXP) { atomicAdd(&imp_acc[tid], s_imp[tid]); atomicAdd(&cnt_acc[tid], s_cnt[tid]); }
  if (tid == 0) atomicAdd(tv_acc, s_tv);
}

// -------------------- weight prep body: W1 stacked [W1;se*W1] + W2 plain
__device__ void btconv_body(
    int j, int e, const float* __restrict__ W1, const float* __restrict__ W2,
    const float* __restrict__ eps, ushort_t* __restrict__ Bt1,
    ushort_t* __restrict__ Bt2)
{
  __shared__ float tile[16][128];
  const int tid = threadIdx.x;
  const int kr = tid >> 5, n4 = (tid & 31) * 4;
  const float* W; int K, jj; float sc; ushort_t* dst;
  if (j < KC1) {
    sc = (j >= 13) ? (1.f + eps[e]) : 1.f;
    jj = (j >= 13) ? (j - 13) : j;
    W = W1; K = CDIM;
    dst = Bt1 + (((size_t)e * KC1 + j) * 256) * 8;
  } else {
    sc = 1.f; jj = j - KC1; W = W2; K = HDIM;
    dst = Bt2 + (((size_t)e * KS2 + jj) * 256) * 8;
  }
#pragma unroll
  for (int h = 0; h < 2; ++h) {
    const int k = jj * 16 + kr + h * 8;
    float4 val = make_float4(0.f, 0.f, 0.f, 0.f);
    if (k < K) val = *(const float4*)(W + ((size_t)e * K + k) * HDIM + n4);
    *(float4*)&tile[kr + h * 8][n4] = val;
  }
  __syncthreads();
  const int kh = tid >> 7, n = tid & 127;
  short8 pk;
#pragma unroll
  for (int q = 0; q < 8; ++q) pk[q] = (short)f2bf(sc * tile[kh * 8 + q][n]);
  *(short8*)(dst + (size_t)tid * 8) = pk;
}

// ---- pass A body: coarse bucket scatter into fixed-capacity bucket slots ----
__device__ void bucketA_body(
    int bid, const int* __restrict__ rows, const int* __restrict__ cols,
    const float* __restrict__ vals, int* __restrict__ bcnt,
    int2* __restrict__ tmp, int ne)
{
  __shared__ int cnt[NB];
  __shared__ int gbase[NB];
  const int tid = threadIdx.x;
  const int base = bid * EPB;
  for (int b = tid; b < NB; b += 256) cnt[b] = 0;
  __syncthreads();
#pragma unroll 4
  for (int j = 0; j < EPB / 256; ++j) {
    const int i = base + j * 256 + tid;
    if (i < ne) atomicAdd(&cnt[rows[i] >> 7], 1);
  }
  __syncthreads();
  for (int b = tid; b < NB; b += 256) {
    const int c = cnt[b];
    gbase[b] = c ? (b * CAP + atomicAdd(&bcnt[b], c)) : 0;
    cnt[b] = 0;
  }
  __syncthreads();
#pragma unroll 4
  for (int j = 0; j < EPB / 256; ++j) {
    const int i = base + j * 256 + tid;
    if (i < ne) {
      const int r = rows[i];
      const int b = r >> 7;
      const int pos = gbase[b] + atomicAdd(&cnt[b], 1);
      tmp[pos] = make_int2((r << 16) | cols[i], __float_as_int(vals[i]));
    }
  }
}

// ---- merged front-end: [gating nGat | btconv 272 | bucketA nA] ----
__global__ __launch_bounds__(256) void prep_kernel(
    const float* __restrict__ v, const float* __restrict__ gW,
    const float* __restrict__ gb, int* __restrict__ top_idx,
    float* __restrict__ top_val, ushort_t* __restrict__ v_bf,
    float* __restrict__ imp_acc, float* __restrict__ cnt_acc,
    float* __restrict__ tv_acc,
    const float* __restrict__ W1, const float* __restrict__ W2,
    const float* __restrict__ eps, ushort_t* __restrict__ Bt1,
    ushort_t* __restrict__ Bt2,
    const int* __restrict__ rows, const int* __restrict__ cols,
    const float* __restrict__ vals, int* __restrict__ bcnt,
    int2* __restrict__ tmp, int ne, int nGat)
{
  const int bid = blockIdx.x;
  if (bid < nGat) {
    gating_body(bid, v, gW, gb, top_idx, top_val, v_bf, imp_acc, cnt_acc, tv_acc);
  } else if (bid < nGat + (KC1 + KS2) * NEXP) {
    const int b2 = bid - nGat;
    btconv_body(b2 % (KC1 + KS2), b2 / (KC1 + KS2), W1, W2, eps, Bt1, Bt2);
  } else {
    bucketA_body(bid - nGat - (KC1 + KS2) * NEXP, rows, cols, vals, bcnt, tmp, ne);
  }
}

// ---- pass B: register-resident bucket; local hist+scan -> row_start/counts,
//      then LDS-cursor scatter into cv
__global__ __launch_bounds__(256) void bucketB_kernel(
    const int2* __restrict__ tmp, const int* __restrict__ bcnt,
    int2* __restrict__ cv, int* __restrict__ row_start, int* __restrict__ counts)
{
  __shared__ int lhist[128];
  __shared__ int lcur[128];
  const int tid = threadIdx.x;
  const int b = blockIdx.x;
  const int n = bcnt[b];
  const int base = b * CAP;
  int2 ed[CAP / 256];
#pragma unroll
  for (int j = 0; j < CAP / 256; ++j) {
    const int i = j * 256 + tid;
    if (i < n) ed[j] = tmp[base + i];
  }
  if (tid < 128) lhist[tid] = 0;
  __syncthreads();
#pragma unroll
  for (int j = 0; j < CAP / 256; ++j)
    if (j * 256 + tid < n)
      atomicAdd(&lhist[(((unsigned)ed[j].x) >> 16) & 127], 1);
  __syncthreads();
  if (tid == 0) {
    int acc = base;
    for (int r = 0; r < 128; ++r) { lcur[r] = acc; acc += lhist[r]; }
  }
  __syncthreads();
  if (tid < 128) {
    row_start[(b << 7) + tid] = lcur[tid];
    counts[(b << 7) + tid] = lhist[tid];
  }
  __syncthreads();
#pragma unroll
  for (int j = 0; j < CAP / 256; ++j)
    if (j * 256 + tid < n) {
      const int r = (((unsigned)ed[j].x) >> 16) & 127;
      const int pos = atomicAdd(&lcur[r], 1);
      cv[pos] = make_int2(ed[j].x & 0xffff, ed[j].y);
    }
}

// aggregate v4: one wave per destination node, 2 edges per gather instruction,
// lane-distributed edge prefetch. node0 = node-range offset (split dispatch).
__global__ __launch_bounds__(256) void aggregate_kernel(
    const ushort_t* __restrict__ v_bf, const int2* __restrict__ cv,
    const int* __restrict__ row_start, const int* __restrict__ counts,
    ushort_t* __restrict__ agg_bf, int node0)
{
  const int node = node0 + ((blockIdx.x * 256 + threadIdx.x) >> 6);
  const int lane = threadIdx.x & 63;
  const int half = lane >> 5;
  const int l32  = lane & 31;
  const bool act = l32 < 26;                // 26 lanes x 8 elems = 208
  const int start = row_start[node];
  const int cnt   = counts[node];

  float acc[8];
#pragma unroll
  for (int j = 0; j < 8; ++j) acc[j] = 0.f;

  int ecol = 0, eval = 0;
  if (lane < cnt) {
    const int2 e = cv[start + lane];
    ecol = e.x; eval = e.y;
  }
  const int n64 = cnt < 64 ? cnt : 64;
  int k = 0;

  for (; k + 16 <= n64; k += 16) {
    short8 xx[8];
#pragma unroll
    for (int u = 0; u < 8; ++u) {
      const int cc = __shfl(ecol, k + 2 * u + half, 64);
      short8 t = {0, 0, 0, 0, 0, 0, 0, 0};
      if (act) t = *(const short8*)(v_bf + (size_t)cc * CPAD + l32 * 8);
      xx[u] = t;
    }
#pragma unroll
    for (int u = 0; u < 8; ++u) {
      const float vv = __int_as_float(__shfl(eval, k + 2 * u + half, 64));
#pragma unroll
      for (int j = 0; j < 8; ++j)
        acc[j] = fmaf(vv, bf2f((ushort_t)xx[u][j]), acc[j]);
    }
  }
  for (; k + 4 <= n64; k += 4) {
    short8 xx[2];
#pragma unroll
    for (int u = 0; u < 2; ++u) {
      const int cc = __shfl(ecol, k + 2 * u + half, 64);
      short8 t = {0, 0, 0, 0, 0, 0, 0, 0};
      if (act) t = *(const short8*)(v_bf + (size_t)cc * CPAD + l32 * 8);
      xx[u] = t;
    }
#pragma unroll
    for (int u = 0; u < 2; ++u) {
      const float vv = __int_as_float(__shfl(eval, k + 2 * u + half, 64));
#pragma unroll
      for (int j = 0; j < 8; ++j)
        acc[j] = fmaf(vv, bf2f((ushort_t)xx[u][j]), acc[j]);
    }
  }
  for (; k < n64; k += 2) {
    const int idx = k + half;
    const int cc = __shfl(ecol, idx, 64);
    short8 t = {0, 0, 0, 0, 0, 0, 0, 0};
    if (act) t = *(const short8*)(v_bf + (size_t)cc * CPAD + l32 * 8);
    const float vv = __int_as_float(__shfl(eval, idx, 64));
#pragma unroll
    for (int j = 0; j < 8; ++j)
      acc[j] = fmaf(vv, bf2f((ushort_t)t[j]), acc[j]);
  }
  for (; k < cnt; ++k) {
    const int2 e0 = cv[start + k];
    short8 x0 = {0, 0, 0, 0, 0, 0, 0, 0};
    if (act && half == 0)
      x0 = *(const short8*)(v_bf + (size_t)e0.x * CPAD + l32 * 8);
    const float v0 = half ? 0.f : __int_as_float(e0.y);
#pragma unroll
    for (int j = 0; j < 8; ++j)
      acc[j] = fmaf(v0, bf2f((ushort_t)x0[j]), acc[j]);
  }

#pragma unroll
  for (int j = 0; j < 8; ++j) acc[j] += __shfl_xor(acc[j], 32, 64);

  if (act && half == 0) {
    short8 o;
#pragma unroll
    for (int j = 0; j < 8; ++j) o[j] = (short)f2bf(acc[j]);
    *(short8*)(agg_bf + (size_t)node * CPAD + l32 * 8) = o;
  }
}

// ---------------------------------------------- GEMM 1: occupancy-split
// acc[2][2] @ 3 blocks/CU; distance-2 B prefetch; sum1/sq1 via part1 stores
// (non-atomic — each (e,col) owned by exactly one wave per block).
__global__ __launch_bounds__(256, 3) void gemm1_mfma(
    const ushort_t* __restrict__ agg_bf, const ushort_t* __restrict__ v_bf,
    const ushort_t* __restrict__ Bt1x, ushort_t* __restrict__ h1,
    float* __restrict__ part1)
{
  const int m0 = blockIdx.x * 64;
  __shared__ ushort_t sA[52 * 64 * 8];       // 53248 B
  const int tid = threadIdx.x;
  const int lane = tid & 63, wid = tid >> 6;
  const int l31 = lane & 31, half = lane >> 5;

#pragma unroll
  for (int it = 0; it < 13; ++it) {
    const int l = it * 256 + tid;
    const int g = l >> 6, m = l & 63;
    const ushort_t* src = (g < 26)
        ? agg_bf + (size_t)(m0 + m) * CPAD + g * 8
        : v_bf  + (size_t)(m0 + m) * CPAD + (g - 26) * 8;
    *(short8*)(sA + (size_t)l * 8) = *(const short8*)src;
  }
  __syncthreads();

#pragma unroll 1
  for (int t = 0; t < 4; ++t) {
    const int e  = wid + (t >> 1) * 4;     // t=0,1 -> e=wid; t=2,3 -> e=wid+4
    const int nh = t & 1;
    floatx16 acc[2][2];
#pragma unroll
    for (int ms = 0; ms < 2; ++ms)
#pragma unroll
      for (int ns = 0; ns < 2; ++ns)
#pragma unroll
        for (int r = 0; r < 16; ++r) acc[ms][ns][r] = 0.f;

    const ushort_t* bte =
        Bt1x + ((size_t)e * KC1 * 256 + half * 128 + nh * 64 + l31) * 8;
    // distance-2 B prefetch pipeline
    short8 p0a = *(const short8*)(bte);
    short8 p0b = *(const short8*)(bte + 32 * 8);
    short8 p1a = *(const short8*)(bte + 256 * 8);
    short8 p1b = *(const short8*)(bte + (256 + 32) * 8);
#pragma unroll
    for (int j = 0; j < KC1; ++j) {
      const short8 b0 = p0a, b1 = p0b;
      p0a = p1a; p0b = p1b;
      if (j < KC1 - 2) {
        p1a = *(const short8*)(bte + (size_t)((j + 2) * 256) * 8);
        p1b = *(const short8*)(bte + (size_t)((j + 2) * 256 + 32) * 8);
      }
      const short8 a0 = *(const short8*)(sA + (size_t)((2 * j + half) * 64 + l31) * 8);
      const short8 a1 = *(const short8*)(sA + (size_t)((2 * j + half) * 64 + 32 + l31) * 8);
      acc[0][0] = __builtin_amdgcn_mfma_f32_32x32x16_bf16(a0, b0, acc[0][0], 0, 0, 0);
      acc[0][1] = __builtin_amdgcn_mfma_f32_32x32x16_bf16(a0, b1, acc[0][1], 0, 0, 0);
      acc[1][0] = __builtin_amdgcn_mfma_f32_32x32x16_bf16(a1, b0, acc[1][0], 0, 0, 0);
      acc[1][1] = __builtin_amdgcn_mfma_f32_32x32x16_bf16(a1, b1, acc[1][1], 0, 0, 0);
    }

    ushort_t* h1e = h1 + ((size_t)e * NNODES + m0) * HDIM;
    const size_t pbase = ((size_t)(e * NBLK1 + blockIdx.x)) * 256;
#pragma unroll
    for (int ns = 0; ns < 2; ++ns) {
      const int col = nh * 64 + ns * 32 + l31;
      float s = 0.f, q = 0.f;
#pragma unroll
      for (int ms = 0; ms < 2; ++ms) {
#pragma unroll
        for (int r = 0; r < 16; ++r) {
          const int row = ms * 32 + (r & 3) + 8 * (r >> 2) + 4 * half;
          const float x = acc[ms][ns][r];
          h1e[(size_t)row * HDIM + col] = f2bf(x);
          s += x; q = fmaf(x, x, q);
        }
      }
      s += __shfl_xor(s, 32, 64);
      q += __shfl_xor(q, 32, 64);
      if (half == 0) {
        part1[pbase + col] = s;          // [0:128) = col sums
        part1[pbase + 128 + col] = q;    // [128:256) = col sq-sums
      }
    }
  }
}

// ---- reduce1: sum part1 over the 800 gemm1 blocks -> sum1/sq1 (memset'd).
// grid (NEXP, 16): each block reduces 50 rows (coalesced), 16-way atomics.
__global__ __launch_bounds__(256) void reduce1_kernel(
    const float* __restrict__ part1, float* __restrict__ sum1,
    float* __restrict__ sq1)
{
  const int e = blockIdx.x, q = blockIdx.y, tid = threadIdx.x;
  const float* base = part1 + ((size_t)(e * NBLK1 + q * (NBLK1 / 16))) * 256 + tid;
  float a0 = 0.f, a1 = 0.f;
#pragma unroll 1
  for (int b = 0; b < NBLK1 / 16; b += 2) {
    a0 += base[(size_t)(b + 0) * 256];
    a1 += base[(size_t)(b + 1) * 256];
  }
  const float acc = a0 + a1;
  if (tid < HDIM) atomicAdd(&sum1[e * HDIM + tid], acc);
  else            atomicAdd(&sq1[e * HDIM + tid - HDIM], acc);
}

// ------------- GEMM 2: BN1 finalize in prologue + single-barrier A staging.
__global__ __launch_bounds__(256, 4) void gemm2_mfma(
    const ushort_t* __restrict__ h1, const ushort_t* __restrict__ Bt2,
    const float* __restrict__ sum1, const float* __restrict__ sq1,
    const float* __restrict__ g1, const float* __restrict__ beta1,
    const int* __restrict__ top_idx, float* __restrict__ h2_sel,
    float* __restrict__ part2)
{
  const int e = blockIdx.y;
  const int m0 = blockIdx.x * 128;
  __shared__ ushort_t sA[16 * 129 * 8];     // 33024 B
  __shared__ float ssum[HDIM], ssq[HDIM];
  __shared__ float sSc[HDIM], sSh[HDIM];
  __shared__ int sTop[128];
  const int tid = threadIdx.x;
  const int lane = tid & 63, wid = tid >> 6;
  const int wm = wid >> 1, wn = wid & 1;
  const int l31 = lane & 31, half = lane >> 5;
  if (tid < HDIM) {
    ssum[tid] = 0.f; ssq[tid] = 0.f;
    sTop[tid] = top_idx[m0 + tid];
    const int i = e * HDIM + tid;
    const float invN = 1.f / (float)NNODES;
    const float mean = sum1[i] * invN;
    const float var  = sq1[i] * invN - mean * mean;
    const float sc = rsqrtf(var + BNEPS) * g1[i];
    sSc[tid] = sc;
    sSh[tid] = fmaf(-mean, sc, beta1[i]);
  }
  __syncthreads();
  {
    const int g = tid & 15, r0 = tid >> 4;
    const float4 sc0 = *(const float4*)&sSc[g * 8];
    const float4 sc1 = *(const float4*)&sSc[g * 8 + 4];
    const float4 sh0 = *(const float4*)&sSh[g * 8];
    const float4 sh1 = *(const float4*)&sSh[g * 8 + 4];
#pragma unroll
    for (int c = 0; c < 8; ++c) {
      const int m = c * 16 + r0;
      const short8 hq = *(const short8*)(
          h1 + ((size_t)e * NNODES + m0 + m) * HDIM + g * 8);
      short8 pk;
      pk[0] = (short)f2bf(fmaxf(0.f, fmaf(bf2f((ushort_t)hq[0]), sc0.x, sh0.x)));
      pk[1] = (short)f2bf(fmaxf(0.f, fmaf(bf2f((ushort_t)hq[1]), sc0.y, sh0.y)));
      pk[2] = (short)f2bf(fmaxf(0.f, fmaf(bf2f((ushort_t)hq[2]), sc0.z, sh0.z)));
      pk[3] = (short)f2bf(fmaxf(0.f, fmaf(bf2f((ushort_t)hq[3]), sc0.w, sh0.w)));
      pk[4] = (short)f2bf(fmaxf(0.f, fmaf(bf2f((ushort_t)hq[4]), sc1.x, sh1.x)));
      pk[5] = (short)f2bf(fmaxf(0.f, fmaf(bf2f((ushort_t)hq[5]), sc1.y, sh1.y)));
      pk[6] = (short)f2bf(fmaxf(0.f, fmaf(bf2f((ushort_t)hq[6]), sc1.z, sh1.z)));
      pk[7] = (short)f2bf(fmaxf(0.f, fmaf(bf2f((ushort_t)hq[7]), sc1.w, sh1.w)));
      *(short8*)(sA + (size_t)(g * 129 + m) * 8) = pk;
    }
  }
  __syncthreads();

  floatx16 acc[2][2];
#pragma unroll
  for (int i = 0; i < 2; ++i)
#pragma unroll
    for (int j = 0; j < 2; ++j)
#pragma unroll
      for (int r = 0; r < 16; ++r) acc[i][j][r] = 0.f;

  const ushort_t* bte = Bt2 + ((size_t)e * KS2 * 256 + half * 128 + wn * 64 + l31) * 8;
  short8 nb0 = *(const short8*)(bte);
  short8 nb1 = *(const short8*)(bte + 32 * 8);
#pragma unroll
  for (int ks = 0; ks < KS2; ++ks) {
    const short8 b0 = nb0, b1 = nb1;
    if (ks < KS2 - 1) {
      nb0 = *(const short8*)(bte + (size_t)((ks + 1) * 256) * 8);
      nb1 = *(const short8*)(bte + (size_t)((ks + 1) * 256 + 32) * 8);
    }
    const short8 a0 = *(const short8*)(sA + (size_t)((2 * ks + half) * 129 + wm * 64 + l31) * 8);
    const short8 a1 = *(const short8*)(sA + (size_t)((2 * ks + half) * 129 + wm * 64 + 32 + l31) * 8);
    acc[0][0] = __builtin_amdgcn_mfma_f32_32x32x16_bf16(a0, b0, acc[0][0], 0, 0, 0);
    acc[0][1] = __builtin_amdgcn_mfma_f32_32x32x16_bf16(a0, b1, acc[0][1], 0, 0, 0);
    acc[1][0] = __builtin_amdgcn_mfma_f32_32x32x16_bf16(a1, b0, acc[1][0], 0, 0, 0);
    acc[1][1] = __builtin_amdgcn_mfma_f32_32x32x16_bf16(a1, b1, acc[1][1], 0, 0, 0);
  }

#pragma unroll
  for (int ms = 0; ms < 2; ++ms)
#pragma unroll
    for (int ns = 0; ns < 2; ++ns) {
      const int col = wn * 64 + ns * 32 + l31;
      float s = 0.f, q = 0.f;
#pragma unroll
      for (int r = 0; r < 16; ++r) {
        const int row = wm * 64 + ms * 32 + (r & 3) + 8 * (r >> 2) + 4 * half;
        const float x = acc[ms][ns][r];
        if (sTop[row] == e) h2_sel[(size_t)(m0 + row) * HDIM + col] = x;
        s += x; q = fmaf(x, x, q);
      }
      atomicAdd(&ssum[col], s);
      atomicAdd(&ssq[col], q);
    }
  __syncthreads();
  part2[((size_t)(e * NBX2 + blockIdx.x)) * 256 + tid] =
      (tid < HDIM) ? ssum[tid] : ssq[tid - HDIM];
}

// ---- reduce2: sum part2 over the 400 gemm2 blocks -> sum2/sq2 (memset'd).
__global__ __launch_bounds__(256) void reduce2_kernel(
    const float* __restrict__ part2, float* __restrict__ sum2,
    float* __restrict__ sq2)
{
  const int e = blockIdx.x, q = blockIdx.y, tid = threadIdx.x;
  const float* base = part2 + ((size_t)(e * NBX2 + q * (NBX2 / 4))) * 256 + tid;
  float a0 = 0.f, a1 = 0.f, a2 = 0.f, a3 = 0.f;
#pragma unroll 1
  for (int b = 0; b < NBX2 / 4; b += 4) {
    a0 += base[(size_t)(b + 0) * 256];
    a1 += base[(size_t)(b + 1) * 256];
    a2 += base[(size_t)(b + 2) * 256];
    a3 += base[(size_t)(b + 3) * 256];
  }
  const float acc = (a0 + a1) + (a2 + a3);
  if (tid < HDIM) atomicAdd(&sum2[e * HDIM + tid], acc);
  else            atomicAdd(&sq2[e * HDIM + tid - HDIM], acc);
}

// --------------------- combine: BN2 finalize in prologue + gate + aux losses
__global__ __launch_bounds__(256) void combine_kernel(
    const float* __restrict__ h2_sel, const int* __restrict__ top_idx,
    const float* __restrict__ top_val, const float* __restrict__ sum2,
    const float* __restrict__ sq2, const float* __restrict__ g2,
    const float* __restrict__ beta2, const float* __restrict__ imp,
    const float* __restrict__ cntv, const float* __restrict__ tv,
    float* __restrict__ out)
{
  __shared__ float s2[NEXP * HDIM], b2s[NEXP * HDIM];
  const int tid = threadIdx.x;
  const float invN = 1.f / (float)NNODES;
  for (int t = tid; t < NEXP * HDIM; t += 256) {
    const float mean = sum2[t] * invN;
    const float var  = sq2[t] * invN - mean * mean;
    const float sc = rsqrtf(var + BNEPS) * g2[t];
    s2[t] = sc;
    b2s[t] = fmaf(-mean, sc, beta2[t]);
  }
  __syncthreads();
  const int i4 = (blockIdx.x * 256 + tid) * 4;
  const int n = i4 >> 7, h = i4 & 127;
  const int e = top_idx[n];
  const float tvv = top_val[n];
  const float4 x = *(const float4*)(h2_sel + i4);
  const float* sc = s2 + e * HDIM + h;
  const float* sh = b2s + e * HDIM + h;
  float4 o;
  o.x = tvv * fmaxf(0.f, fmaf(x.x, sc[0], sh[0]));
  o.y = tvv * fmaxf(0.f, fmaf(x.y, sc[1], sh[1]));
  o.z = tvv * fmaxf(0.f, fmaf(x.z, sc[2], sh[2]));
  o.w = tvv * fmaxf(0.f, fmaf(x.w, sc[3], sh[3]));
  *(float4*)(out + i4) = o;
  if (blockIdx.x == 0 && tid == 0) {
    float bal = 0.f;
#pragma unroll
    for (int q = 0; q < NEXP; ++q) bal += (imp[q] * invN) * (cntv[q] * invN);
    out[(size_t)NNODES * HDIM]     = 0.01f * (float)NEXP * bal;
    out[(size_t)NNODES * HDIM + 1] = -0.01f * tv[0] * invN;
  }
}

// ----------------------------------------------------------------- launch
struct WS {
  ushort_t *v_bf, *agg_bf, *h1, *Bt1x, *Bt2;
  float *h2_sel, *part1, *part2;
  int2 *cv, *tmp;
  int *row_start, *counts, *top_idx;
  float *top_val;
  char *zero_base; size_t zero_bytes;
  int *bcnt;
  float *sum1, *sq1, *sum2, *sq2, *imp, *cnt, *tv;
  size_t total;
};

static WS carve_ws(char* base)
{
  WS w; size_t off = 0;
  auto take = [&](size_t b) -> char* {
    char* r = base + off; off += (b + 255) & ~(size_t)255; return r;
  };
  // v_bf (21.3 MB) + agg_bf (21.3 MB) adjacent; h2_sel alias (26.2 MB f32)
  // spills from v_bf into agg_bf, which is dead after gemm1.
  w.v_bf   = (ushort_t*)take((size_t)NNODES * CPAD * 2);
  w.agg_bf = (ushort_t*)take((size_t)NNODES * CPAD * 2);
  w.h2_sel = (float*)w.v_bf;
  w.h1     = (ushort_t*)take((size_t)NEXP * NNODES * HDIM * 2);
  w.cv     = (int2*)take((size_t)NB * CAP * 8);
  w.tmp    = (int2*)take((size_t)NB * CAP * 8);
  w.Bt1x   = (ushort_t*)take((size_t)NEXP * KC1 * 2048 * 2);
  w.Bt2    = (ushort_t*)take((size_t)NEXP * KS2 * 2048 * 2);
  w.part1  = (float*)take((size_t)NEXP * NBLK1 * 256 * 4);  // 6.55 MB, fully written
  w.part2  = (float*)take((size_t)NEXP * NBX2 * 256 * 4);   // 3.3 MB, fully written
  w.row_start = (int*)take(NNODES * 4);
  w.counts    = (int*)take(NNODES * 4);
  w.top_idx   = (int*)take(NNODES * 4);
  w.top_val   = (float*)take(NNODES * 4);
  w.zero_base = base + off;
  w.bcnt = (int*)take(NB * 4);
  w.sum1 = (float*)take(NEXP * HDIM * 4);
  w.sq1  = (float*)take(NEXP * HDIM * 4);
  w.sum2 = (float*)take(NEXP * HDIM * 4);
  w.sq2  = (float*)take(NEXP * HDIM * 4);
  w.imp  = (float*)take(NEXP * 4);
  w.cnt  = (float*)take(NEXP * 4);
  w.tv   = (float*)take(4);
  w.zero_bytes = (size_t)((base + off) - w.zero_base);
  w.total = off;
  return w;
}

extern "C" void kernel_launch(void* const* d_in, const int* in_sizes, int n_in,
                              void* d_out, int out_size, void* d_ws, size_t ws_size,
                              hipStream_t stream)
{
  const float* v      = (const float*)d_in[0];
  const int*   a_rows = (const int*)d_in[1];
  const int*   a_cols = (const int*)d_in[2];
  const float* a_vals = (const float*)d_in[3];
  const float* gate_W = (const float*)d_in[4];
  const float* gate_b = (const float*)d_in[5];
  const float* eps    = (const float*)d_in[6];
  const float* W1     = (const float*)d_in[7];
  const float* g1     = (const float*)d_in[9];
  const float* beta1  = (const float*)d_in[10];
  const float* W2     = (const float*)d_in[11];
  const float* g2     = (const float*)d_in[13];
  const float* beta2  = (const float*)d_in[14];
  const int NE = in_sizes[1];
  float* out = (float*)d_out;
  (void)n_in; (void)out_size; (void)ws_size;

  WS w = carve_ws((char*)d_ws);

  hipMemsetAsync(w.zero_base, 0, w.zero_bytes, stream);

  const int nGat = NNODES / 32;                       // 1600
  const int nBtc = (KC1 + KS2) * NEXP;                // 272
  const int nA   = (NE + EPB - 1) / EPB;              // 400
  prep_kernel<<<nGat + nBtc + nA, 256, 0, stream>>>(
      v, gate_W, gate_b, w.top_idx, w.top_val, w.v_bf, w.imp, w.cnt, w.tv,
      W1, W2, eps, w.Bt1x, w.Bt2,
      a_rows, a_cols, a_vals, w.bcnt, w.tmp, NE, nGat);

  bucketB_kernel<<<NB, 256, 0, stream>>>(
      w.tmp, w.bcnt, w.cv, w.row_start, w.counts);

  // aggregate split into two half-dispatches (instrumentation/visibility)
  aggregate_kernel<<<NNODES / 8, 256, 0, stream>>>(
      w.v_bf, w.cv, w.row_start, w.counts, w.agg_bf, 0);
  aggregate_kernel<<<NNODES / 8, 256, 0, stream>>>(
      w.v_bf, w.cv, w.row_start, w.counts, w.agg_bf, NNODES / 2);

  gemm1_mfma<<<NBLK1, 256, 0, stream>>>(
      w.agg_bf, w.v_bf, w.Bt1x, w.h1, w.part1);
  reduce1_kernel<<<dim3(NEXP, 16), 256, 0, stream>>>(
      w.part1, w.sum1, w.sq1);
  gemm2_mfma<<<dim3(NBX2, NEXP), 256, 0, stream>>>(
      w.h1, w.Bt2, w.sum1, w.sq1, g1, beta1, w.top_idx,
      w.h2_sel, w.part2);
  reduce2_kernel<<<dim3(NEXP, 4), 256, 0, stream>>>(
      w.part2, w.sum2, w.sq2);
  combine_kernel<<<(NNODES * HDIM) / 1024, 256, 0, stream>>>(
      w.h2_sel, w.top_idx, w.top_val, w.sum2, w.sq2, g2, beta2,
      w.imp, w.cnt, w.tv, out);
}